// Round 1
// baseline (2073.141 us; speedup 1.0000x reference)
//
#include <hip/hip_runtime.h>
#include <stdint.h>
#include <math.h>

#define NLEV 5
#define NIMG 16
#define NCLS 80
#define TOPK 1000
#define MTOT 5000
#define SORTN 8192
#define BINBCAP 4096
#define NBINS 288
#define BIN0 7846
#define OUTK 100
#define TOTAL_ELEMS 25941760

__device__ __constant__ int c_HW[NLEV]   = {15200, 3800, 950, 247, 70};
__device__ __constant__ int c_E[NLEV]    = {1216000, 304000, 76000, 19760, 5600};
__device__ __constant__ int c_base[NLEV + 1] = {0, 19456000, 24320000, 25536000, 25852160, 25941760};

struct Params {
    const float* cls[NLEV];
    const float* reg[NLEV];
    const float* anc[NLEV];
    const int* imsize;
};

// ---- shared decode (must be used identically by k_keys and k_prep) ----
__device__ inline void decode_entry(const Params& P, int img, int lvl, uint32_t idx,
                                    float bclip[4], int* cls_out, bool* nonempty) {
    int HW = c_HW[lvl];
    int loc = (int)idx / NCLS;
    int c = (int)idx - loc * NCLS;
    const float* a = P.anc[lvl] + 4 * loc;
    float a0 = a[0], a1 = a[1], a2 = a[2], a3 = a[3];
    const float* rg = P.reg[lvl] + (size_t)img * 4 * HW + loc;
    float d0 = rg[0], d1 = rg[HW], d2 = rg[2 * HW], d3 = rg[3 * HW];
    float w = a2 - a0 + 1.0f, h = a3 - a1 + 1.0f;
    float cx = a0 + 0.5f * w, cy = a1 + 0.5f * h;
    float dx = d0 / 10.0f, dy = d1 / 10.0f;
    const float SCALE_CLAMP = 4.135166556742356f;
    float dw = fminf(d2 / 5.0f, SCALE_CLAMP);
    float dh = fminf(d3 / 5.0f, SCALE_CLAMP);
    float pcx = dx * w + cx, pcy = dy * h + cy;
    float pw = (float)exp((double)dw) * w;
    float ph = (float)exp((double)dh) * h;
    float x1 = pcx - 0.5f * (pw - 1.0f), y1 = pcy - 0.5f * (ph - 1.0f);
    float x2 = pcx + 0.5f * (pw - 1.0f), y2 = pcy + 0.5f * (ph - 1.0f);
    float Hs = (float)P.imsize[img * 2 + 0];
    float Ws = (float)P.imsize[img * 2 + 1];
    float x1c = fminf(fmaxf(x1, 0.0f), Ws);
    float y1c = fminf(fmaxf(y1, 0.0f), Hs);
    float x2c = fminf(fmaxf(x2, 0.0f), Ws);
    float y2c = fminf(fmaxf(y2, 0.0f), Hs);
    bclip[0] = x1c; bclip[1] = y1c; bclip[2] = x2c; bclip[3] = y2c;
    *cls_out = c;
    *nonempty = ((x2c - x1c) > 0.0f) && ((y2c - y1c) > 0.0f);
}

__device__ inline float sigmoid_f(float x) {
    return (float)(1.0 / (1.0 + exp(-(double)x)));
}

// ---- K1: histogram of score bits per (level,img) row ----
__global__ __launch_bounds__(256) void k_hist(Params P, uint32_t* hist) {
    int stride = gridDim.x * blockDim.x;
    for (int t = blockIdx.x * blockDim.x + threadIdx.x; t < TOTAL_ELEMS; t += stride) {
        int l = 0;
#pragma unroll
        for (int q = 1; q < NLEV; q++) if (t >= c_base[q]) l = q;
        int r = t - c_base[l];
        int E = c_E[l];
        int img = r / E;
        float s = sigmoid_f(P.cls[l][r]);
        if (s > 0.05f) {
            uint32_t bits = __float_as_uint(s);
            int bin = (int)(bits >> 17) - BIN0;
            int row = l * NIMG + img;
            atomicAdd(&hist[row * NBINS + bin], 1u);
        }
    }
}

// ---- K2: scan histogram top-down to find boundary bin ----
__global__ void k_scan(const uint32_t* hist, int* sel) {
    __shared__ uint32_t h[NBINS];
    int row = blockIdx.x;
    for (int b = threadIdx.x; b < NBINS; b += blockDim.x) h[b] = hist[row * NBINS + b];
    __syncthreads();
    if (threadIdx.x == 0) {
        int cum = 0, B = -1, need = 0, cab = 0;
        for (int b = NBINS - 1; b >= 0; b--) {
            int c = (int)h[b];
            if (cum + c >= TOPK) { B = b; cab = cum; need = TOPK - cum; break; }
            cum += c;
        }
        if (B < 0) { cab = cum; need = 0; }
        sel[row * 4 + 0] = B;
        sel[row * 4 + 1] = cab;
        sel[row * 4 + 2] = need;
        sel[row * 4 + 3] = cum;
    }
}

// ---- K3: compact candidates: bins>B direct, bin==B to boundary list ----
__global__ __launch_bounds__(256) void k_compact(Params P, const int* sel, uint32_t* outCand,
                                                 uint32_t* outCount, uint32_t* binB, uint32_t* binBCnt) {
    int stride = gridDim.x * blockDim.x;
    for (int t = blockIdx.x * blockDim.x + threadIdx.x; t < TOTAL_ELEMS; t += stride) {
        int l = 0;
#pragma unroll
        for (int q = 1; q < NLEV; q++) if (t >= c_base[q]) l = q;
        int r = t - c_base[l];
        int E = c_E[l];
        int img = r / E;
        float s = sigmoid_f(P.cls[l][r]);
        if (s > 0.05f) {
            uint32_t bits = __float_as_uint(s);
            int bin = (int)(bits >> 17) - BIN0;
            int row = l * NIMG + img;
            int B = sel[row * 4 + 0];
            if (bin > B) {
                uint32_t pos = atomicAdd(&outCount[row], 1u);
                if (pos < TOPK) {
                    int q2 = r - img * E;
                    int HW = c_HW[l];
                    int c = q2 / HW;
                    int p = q2 - c * HW;
                    uint32_t idx = (uint32_t)(p * NCLS + c);
                    outCand[((size_t)row * TOPK + pos) * 2 + 0] = bits;
                    outCand[((size_t)row * TOPK + pos) * 2 + 1] = idx;
                }
            } else if (bin == B) {
                uint32_t p2 = atomicAdd(&binBCnt[row], 1u);
                if (p2 < BINBCAP) {
                    int q2 = r - img * E;
                    int HW = c_HW[l];
                    int c = q2 / HW;
                    int p = q2 - c * HW;
                    uint32_t idx = (uint32_t)(p * NCLS + c);
                    binB[((size_t)row * BINBCAP + p2) * 2 + 0] = bits;
                    binB[((size_t)row * BINBCAP + p2) * 2 + 1] = idx;
                }
            }
        }
    }
}

// ---- K4: exact sort of boundary bin, append `need` winners ----
__global__ __launch_bounds__(256) void k_selsort(const int* sel, const uint32_t* binB,
                                                 const uint32_t* binBCnt, uint32_t* outCand) {
    __shared__ uint64_t sk[BINBCAP];
    int row = blockIdx.x;
    int need = sel[row * 4 + 2];
    int cab = sel[row * 4 + 1];
    if (need <= 0) return;
    int cnt = min((int)binBCnt[row], BINBCAP);
    for (int i = threadIdx.x; i < BINBCAP; i += blockDim.x) {
        uint64_t key = ~0ULL;
        if (i < cnt) {
            uint32_t b = binB[((size_t)row * BINBCAP + i) * 2 + 0];
            uint32_t idx = binB[((size_t)row * BINBCAP + i) * 2 + 1];
            key = ((uint64_t)(uint32_t)(~b) << 32) | idx;   // value desc, idx asc
        }
        sk[i] = key;
    }
    __syncthreads();
    for (int k = 2; k <= BINBCAP; k <<= 1) {
        for (int j = k >> 1; j > 0; j >>= 1) {
            for (int i = threadIdx.x; i < BINBCAP; i += blockDim.x) {
                int ixj = i ^ j;
                if (ixj > i) {
                    uint64_t A = sk[i], Bv = sk[ixj];
                    bool up = ((i & k) == 0);
                    if (up ? (A > Bv) : (A < Bv)) { sk[i] = Bv; sk[ixj] = A; }
                }
            }
            __syncthreads();
        }
    }
    int take = min(need, cnt);
    for (int i = threadIdx.x; i < take; i += blockDim.x) {
        uint64_t k = sk[i];
        uint32_t idx = (uint32_t)(k & 0xFFFFFFFFu);
        uint32_t bits = ~((uint32_t)(k >> 32));
        int pos = cab + i;
        outCand[((size_t)row * TOPK + pos) * 2 + 0] = bits;
        outCand[((size_t)row * TOPK + pos) * 2 + 1] = idx;
    }
}

// ---- K5: build 64-bit sort keys (post-nonempty score, ref tie order) ----
__global__ __launch_bounds__(256) void k_keys(Params P, const uint32_t* outCand, uint64_t* keys) {
    int t = blockIdx.x * blockDim.x + threadIdx.x;
    if (t >= NIMG * SORTN) return;
    int img = t / SORTN;
    int e = t - img * SORTN;
    if (e >= MTOT) { keys[t] = ~0ULL; return; }
    int lvl = e / TOPK;
    int slot = e - lvl * TOPK;
    int row = lvl * NIMG + img;
    uint32_t bits = outCand[((size_t)row * TOPK + slot) * 2 + 0];
    uint32_t idx = outCand[((size_t)row * TOPK + slot) * 2 + 1];
    uint32_t be = 0;
    if (bits != 0) {
        float bc[4]; int cc; bool ne;
        decode_entry(P, img, lvl, idx, bc, &cc, &ne);
        if (ne) be = bits;
    }
    keys[(size_t)img * SORTN + e] =
        ((uint64_t)(uint32_t)(~be) << 24) | ((uint64_t)lvl << 21) | (uint64_t)idx;
}

// ---- K6: per-image bitonic sort of 8192 keys (global memory) ----
__global__ __launch_bounds__(1024) void k_sort(uint64_t* keys) {
    uint64_t* g = keys + (size_t)blockIdx.x * SORTN;
    for (int k = 2; k <= SORTN; k <<= 1) {
        for (int j = k >> 1; j > 0; j >>= 1) {
            for (int i = threadIdx.x; i < SORTN; i += blockDim.x) {
                int ixj = i ^ j;
                if (ixj > i) {
                    uint64_t A = g[i], Bv = g[ixj];
                    bool up = ((i & k) == 0);
                    if (up ? (A > Bv) : (A < Bv)) { g[i] = Bv; g[ixj] = A; }
                }
            }
            __syncthreads();
        }
    }
}

// ---- K7: decode sorted entries into NMS-ready arrays ----
__global__ __launch_bounds__(256) void k_prep(Params P, const uint64_t* keys, float4* boff,
                                              float* area, float4* bclip, float* scs, int* clss) {
    int t = blockIdx.x * blockDim.x + threadIdx.x;
    if (t >= NIMG * MTOT) return;
    int img = t / MTOT;
    int e = t - img * MTOT;
    uint64_t k = keys[(size_t)img * SORTN + e];
    uint32_t bits = ~((uint32_t)(k >> 24));
    int lvl = (int)((k >> 21) & 7);
    uint32_t idx = (uint32_t)(k & 0x1FFFFF);
    float bc[4]; int cc; bool ne;
    decode_entry(P, img, lvl, idx, bc, &cc, &ne);
    float sc = 0.0f;
    if (bits != 0) {
        float s = __uint_as_float(bits);
        sc = sqrtf(fmaxf(s, 1e-12f));
    }
    float off = (float)cc * 2000.0f;
    float b0 = bc[0] + off, b1 = bc[1] + off, b2 = bc[2] + off, b3 = bc[3] + off;
    boff[t] = make_float4(b0, b1, b2, b3);
    area[t] = (b2 - b0) * (b3 - b1);
    bclip[t] = make_float4(bc[0], bc[1], bc[2], bc[3]);
    scs[t] = sc;
    clss[t] = cc;
}

// ---- K8: per-image sequential greedy NMS with early exit, write outputs ----
__global__ __launch_bounds__(256) void k_nms(const float4* boff, const float* area,
                                             const float4* bclip, const float* scs,
                                             const int* clss, float* out) {
    int img = blockIdx.x;
    const float4* bo = boff + (size_t)img * MTOT;
    const float* ar = area + (size_t)img * MTOT;
    const float4* bclp = bclip + (size_t)img * MTOT;
    const float* sc = scs + (size_t)img * MTOT;
    const int* cl = clss + (size_t)img * MTOT;
    __shared__ uint32_t sup[(MTOT + 31) / 32 + 1];  // 157 words
    __shared__ int kept[OUTK];
    int tid = threadIdx.x;
    const int NW = (MTOT + 31) / 32;
    for (int w = tid; w < NW; w += 256) {
        uint32_t m = 0;
        for (int b = 0; b < 32; b++) {
            int e = w * 32 + b;
            bool s = (e >= MTOT) || (sc[e] == 0.0f);
            m |= (s ? 1u : 0u) << b;
        }
        sup[w] = m;
    }
    __syncthreads();
    int kc = 0;
    for (int i = 0; i < MTOT; i++) {
        if ((sup[i >> 5] >> (i & 31)) & 1u) continue;
        if (tid == 0) kept[kc] = i;
        float4 bi = bo[i];
        float ai = ar[i];
        for (int j = i + 1 + tid; j < MTOT; j += 256) {
            float4 bj = bo[j];
            float xx1 = fmaxf(bi.x, bj.x), yy1 = fmaxf(bi.y, bj.y);
            float xx2 = fminf(bi.z, bj.z), yy2 = fminf(bi.w, bj.w);
            float inter = fmaxf(xx2 - xx1, 0.0f) * fmaxf(yy2 - yy1, 0.0f);
            float iou = inter / (ai + ar[j] - inter + 1e-9f);
            if (iou > 0.6f) atomicOr(&sup[j >> 5], 1u << (j & 31));
        }
        kc++;
        __syncthreads();
        if (kc == OUTK) break;
    }
    if (tid == 0) {
        int k2 = kc;
        for (int e = 0; e < MTOT && k2 < OUTK; e++) {
            if ((sup[e >> 5] >> (e & 31)) & 1u) kept[k2++] = e | (1 << 30);
        }
    }
    __syncthreads();
    for (int t = tid; t < OUTK; t += 256) {
        int ke = kept[t];
        bool fil = (ke >> 30) & 1;
        int e = ke & 0x3FFFFFFF;
        float4 b = bclp[e];
        out[((size_t)img * OUTK + t) * 4 + 0] = b.x;
        out[((size_t)img * OUTK + t) * 4 + 1] = b.y;
        out[((size_t)img * OUTK + t) * 4 + 2] = b.z;
        out[((size_t)img * OUTK + t) * 4 + 3] = b.w;
        out[NIMG * OUTK * 4 + img * OUTK + t] = fil ? 0.0f : sc[e];
        out[NIMG * OUTK * 4 + NIMG * OUTK + img * OUTK + t] = (float)cl[e];
    }
}

extern "C" void kernel_launch(void* const* d_in, const int* in_sizes, int n_in,
                              void* d_out, int out_size, void* d_ws, size_t ws_size,
                              hipStream_t stream) {
    Params P;
    for (int l = 0; l < 5; l++) {
        P.cls[l] = (const float*)d_in[l * 3 + 0];
        P.reg[l] = (const float*)d_in[l * 3 + 1];
        P.anc[l] = (const float*)d_in[l * 3 + 2];
    }
    P.imsize = (const int*)d_in[15];

    char* w = (char*)d_ws;
    // layout (bytes)
    uint32_t* hist     = (uint32_t*)(w + 0);        // 80*288*4      = 92160
    int*      sel      = (int*)(w + 92160);         // 80*4*4        = 1280
    uint32_t* outCount = (uint32_t*)(w + 93440);    // 80*4          = 320
    uint32_t* binBCnt  = (uint32_t*)(w + 93760);    // 80*4          = 320
    uint32_t* outCand  = (uint32_t*)(w + 94080);    // 80*1000*2*4   = 640000
    uint32_t* binB     = (uint32_t*)(w + 734080);   // 80*4096*2*4   = 2621440
    uint64_t* keys     = (uint64_t*)(w + 3355520);  // 16*8192*8     = 1048576
    float4*   boff     = (float4*)(w + 4404096);    // 16*5000*16    = 1280000
    float*    area     = (float*)(w + 5684096);     // 16*5000*4     = 320000
    float4*   bclipb   = (float4*)(w + 6004096);    // 16*5000*16    = 1280000
    float*    scs      = (float*)(w + 7284096);     // 16*5000*4     = 320000
    int*      clss     = (int*)(w + 7604096);       // 16*5000*4     = 320000
    // total 7924096 bytes

    hipMemsetAsync(w, 0, 734080, stream);  // hist + sel + counters + outCand

    k_hist<<<8192, 256, 0, stream>>>(P, hist);
    k_scan<<<80, 64, 0, stream>>>(hist, sel);
    k_compact<<<8192, 256, 0, stream>>>(P, sel, outCand, outCount, binB, binBCnt);
    k_selsort<<<80, 256, 0, stream>>>(sel, binB, binBCnt, outCand);
    k_keys<<<(NIMG * SORTN + 255) / 256, 256, 0, stream>>>(P, outCand, keys);
    k_sort<<<NIMG, 1024, 0, stream>>>(keys);
    k_prep<<<(NIMG * MTOT + 255) / 256, 256, 0, stream>>>(P, keys, boff, area, bclipb, scs, clss);
    k_nms<<<NIMG, 256, 0, stream>>>(boff, area, bclipb, scs, clss, (float*)d_out);
}

// Round 2
// 1095.432 us; speedup vs baseline: 1.8925x; 1.8925x over previous
//
#include <hip/hip_runtime.h>
#include <stdint.h>
#include <math.h>

#define NLEV 5
#define NIMG 16
#define NCLS 80
#define TOPK 1000
#define MTOT 5000
#define SORTN 8192
#define BINBCAP 4096
#define NBINS 288
#define BIN0 7846
#define OUTK 100
#define CHUNK 16384

__device__ __constant__ int c_HW[NLEV]   = {15200, 3800, 950, 247, 70};
__device__ __constant__ int c_E[NLEV]    = {1216000, 304000, 76000, 19760, 5600};
__device__ __constant__ int c_cpr[NLEV]  = {75, 19, 5, 2, 1};            // chunks per (img,level) row
__device__ __constant__ int c_cbase[NLEV + 1] = {0, 1200, 1504, 1584, 1616, 1632};

struct Params {
    const float* cls[NLEV];
    const float* reg[NLEV];
    const float* anc[NLEV];
    const int* imsize;
};

// ---- shared decode (must be used identically by k_keys and k_prep) ----
__device__ inline void decode_entry(const Params& P, int img, int lvl, uint32_t idx,
                                    float bclip[4], int* cls_out, bool* nonempty) {
    int HW = c_HW[lvl];
    int loc = (int)idx / NCLS;
    int c = (int)idx - loc * NCLS;
    const float* a = P.anc[lvl] + 4 * loc;
    float a0 = a[0], a1 = a[1], a2 = a[2], a3 = a[3];
    const float* rg = P.reg[lvl] + (size_t)img * 4 * HW + loc;
    float d0 = rg[0], d1 = rg[HW], d2 = rg[2 * HW], d3 = rg[3 * HW];
    float w = a2 - a0 + 1.0f, h = a3 - a1 + 1.0f;
    float cx = a0 + 0.5f * w, cy = a1 + 0.5f * h;
    float dx = d0 / 10.0f, dy = d1 / 10.0f;
    const float SCALE_CLAMP = 4.135166556742356f;
    float dw = fminf(d2 / 5.0f, SCALE_CLAMP);
    float dh = fminf(d3 / 5.0f, SCALE_CLAMP);
    float pcx = dx * w + cx, pcy = dy * h + cy;
    float pw = (float)exp((double)dw) * w;
    float ph = (float)exp((double)dh) * h;
    float x1 = pcx - 0.5f * (pw - 1.0f), y1 = pcy - 0.5f * (ph - 1.0f);
    float x2 = pcx + 0.5f * (pw - 1.0f), y2 = pcy + 0.5f * (ph - 1.0f);
    float Hs = (float)P.imsize[img * 2 + 0];
    float Ws = (float)P.imsize[img * 2 + 1];
    float x1c = fminf(fmaxf(x1, 0.0f), Ws);
    float y1c = fminf(fmaxf(y1, 0.0f), Hs);
    float x2c = fminf(fmaxf(x2, 0.0f), Ws);
    float y2c = fminf(fmaxf(y2, 0.0f), Hs);
    bclip[0] = x1c; bclip[1] = y1c; bclip[2] = x2c; bclip[3] = y2c;
    *cls_out = c;
    *nonempty = ((x2c - x1c) > 0.0f) && ((y2c - y1c) > 0.0f);
}

__device__ inline float sigmoid_f(float x) {
    return (float)(1.0 / (1.0 + exp(-(double)x)));
}

// ordered-uint <-> float (monotone bijection) for threshold bisection
__device__ inline uint32_t f2o(float f) {
    uint32_t b = __float_as_uint(f);
    return (b & 0x80000000u) ? ~b : (b | 0x80000000u);
}
__device__ inline float o2f(uint32_t o) {
    uint32_t b = (o & 0x80000000u) ? (o & 0x7FFFFFFFu) : ~o;
    return __uint_as_float(b);
}

// chunk -> (level, img, element range) mapping shared by k_hist / k_pass2
__device__ inline void chunk_map(int bid, int* lvl, int* img, int* start, int* end) {
    int l = 0;
#pragma unroll
    for (int q = 1; q < NLEV; q++) if (bid >= c_cbase[q]) l = q;
    int r = bid - c_cbase[l];
    int cpr = c_cpr[l];
    int im = r / cpr;
    int ch = r - im * cpr;
    int E = c_E[l];
    int st = ch * CHUNK;
    *lvl = l; *img = im; *start = st; *end = min(st + CHUNK, E);
}

// ---- K1: per-chunk LDS histogram of score bits ----
__global__ __launch_bounds__(256) void k_hist(Params P, uint32_t* hist) {
    __shared__ uint32_t lh[NBINS];
    int l, img, start, end;
    chunk_map(blockIdx.x, &l, &img, &start, &end);
    for (int b = threadIdx.x; b < NBINS; b += 256) lh[b] = 0;
    __syncthreads();
    const float4* p = (const float4*)(P.cls[l] + (size_t)img * c_E[l] + start);
    int n4 = (end - start) >> 2;
    for (int v = threadIdx.x; v < n4; v += 256) {
        float4 x4 = p[v];
        float xs[4] = {x4.x, x4.y, x4.z, x4.w};
#pragma unroll
        for (int k = 0; k < 4; k++) {
            float xv = xs[k];
            if (xv >= -2.95f) {              // sigmoid(-2.95)=0.0497<0.05 -> safe skip
                float s = sigmoid_f(xv);
                if (s > 0.05f) {
                    int bin = (int)(__float_as_uint(s) >> 17) - BIN0;
                    atomicAdd(&lh[bin], 1u);
                }
            }
        }
    }
    __syncthreads();
    int row = l * NIMG + img;
    for (int b = threadIdx.x; b < NBINS; b += 256) {
        uint32_t c = lh[b];
        if (c) atomicAdd(&hist[row * NBINS + b], c);
    }
}

// ---- K2: scan histogram top-down; bisect exact logit threshold per row ----
__global__ void k_scan(const uint32_t* hist, int* sel, float* xth) {
    int row = blockIdx.x;
    if (threadIdx.x != 0) return;
    int cum = 0, B = -1, need = 0, cab = 0;
    for (int b = NBINS - 1; b >= 0; b--) {
        int c = (int)hist[row * NBINS + b];
        if (cum + c >= TOPK) { B = b; cab = cum; need = TOPK - cum; break; }
        cum += c;
    }
    if (B < 0) { cab = cum; need = 0; }
    sel[row * 4 + 0] = B;
    sel[row * 4 + 1] = cab;
    sel[row * 4 + 2] = need;
    sel[row * 4 + 3] = cum;
    // minimal float x with (sigmoid_f(x) > 0.05f && bin >= B); predicate monotone in x
    uint32_t lo = f2o(-4.0f), hi = f2o(20.0f);
    while (hi - lo > 1u) {
        uint32_t mid = lo + ((hi - lo) >> 1);
        float xm = o2f(mid);
        float s = sigmoid_f(xm);
        bool pass = (s > 0.05f) &&
                    (B < 0 || ((int)(__float_as_uint(s) >> 17) - BIN0) >= B);
        if (pass) hi = mid; else lo = mid;
    }
    xth[row] = o2f(hi);
}

// ---- K3: compact candidates (cheap float-compare filter, rare atomics) ----
__global__ __launch_bounds__(256) void k_pass2(Params P, const int* sel, const float* xth,
                                               uint32_t* outCand, uint32_t* outCount,
                                               uint32_t* binB, uint32_t* binBCnt) {
    int l, img, start, end;
    chunk_map(blockIdx.x, &l, &img, &start, &end);
    int row = l * NIMG + img;
    float xt = xth[row];
    int B = sel[row * 4 + 0];
    int HW = c_HW[l];
    const float4* p = (const float4*)(P.cls[l] + (size_t)img * c_E[l] + start);
    int n4 = (end - start) >> 2;
    for (int v = threadIdx.x; v < n4; v += 256) {
        float4 x4 = p[v];
        float xs[4] = {x4.x, x4.y, x4.z, x4.w};
#pragma unroll
        for (int k = 0; k < 4; k++) {
            float xv = xs[k];
            if (xv >= xt) {                       // implies s>0.05f && bin>=B
                float s = sigmoid_f(xv);
                uint32_t bits = __float_as_uint(s);
                int bin = (int)(bits >> 17) - BIN0;
                int q2 = start + v * 4 + k;       // c*HW + p layout
                int c = q2 / HW;
                int pidx = q2 - c * HW;
                uint32_t idx = (uint32_t)(pidx * NCLS + c);
                if (bin > B) {
                    uint32_t pos = atomicAdd(&outCount[row], 1u);
                    if (pos < TOPK) {
                        outCand[((size_t)row * TOPK + pos) * 2 + 0] = bits;
                        outCand[((size_t)row * TOPK + pos) * 2 + 1] = idx;
                    }
                } else {
                    uint32_t p2 = atomicAdd(&binBCnt[row], 1u);
                    if (p2 < BINBCAP) {
                        binB[((size_t)row * BINBCAP + p2) * 2 + 0] = bits;
                        binB[((size_t)row * BINBCAP + p2) * 2 + 1] = idx;
                    }
                }
            }
        }
    }
}

// ---- K4: exact sort of boundary bin, append `need` winners ----
__global__ __launch_bounds__(256) void k_selsort(const int* sel, const uint32_t* binB,
                                                 const uint32_t* binBCnt, uint32_t* outCand) {
    __shared__ uint64_t sk[BINBCAP];
    int row = blockIdx.x;
    int need = sel[row * 4 + 2];
    int cab = sel[row * 4 + 1];
    if (need <= 0) return;
    int cnt = min((int)binBCnt[row], BINBCAP);
    for (int i = threadIdx.x; i < BINBCAP; i += blockDim.x) {
        uint64_t key = ~0ULL;
        if (i < cnt) {
            uint32_t b = binB[((size_t)row * BINBCAP + i) * 2 + 0];
            uint32_t idx = binB[((size_t)row * BINBCAP + i) * 2 + 1];
            key = ((uint64_t)(uint32_t)(~b) << 32) | idx;   // value desc, idx asc
        }
        sk[i] = key;
    }
    __syncthreads();
    for (int k = 2; k <= BINBCAP; k <<= 1) {
        for (int j = k >> 1; j > 0; j >>= 1) {
            for (int i = threadIdx.x; i < BINBCAP; i += blockDim.x) {
                int ixj = i ^ j;
                if (ixj > i) {
                    uint64_t A = sk[i], Bv = sk[ixj];
                    bool up = ((i & k) == 0);
                    if (up ? (A > Bv) : (A < Bv)) { sk[i] = Bv; sk[ixj] = A; }
                }
            }
            __syncthreads();
        }
    }
    int take = min(need, cnt);
    for (int i = threadIdx.x; i < take; i += blockDim.x) {
        uint64_t k = sk[i];
        uint32_t idx = (uint32_t)(k & 0xFFFFFFFFu);
        uint32_t bits = ~((uint32_t)(k >> 32));
        int pos = cab + i;
        outCand[((size_t)row * TOPK + pos) * 2 + 0] = bits;
        outCand[((size_t)row * TOPK + pos) * 2 + 1] = idx;
    }
}

// ---- K5: build 64-bit sort keys (post-nonempty score, ref tie order) ----
__global__ __launch_bounds__(256) void k_keys(Params P, const uint32_t* outCand, uint64_t* keys) {
    int t = blockIdx.x * blockDim.x + threadIdx.x;
    if (t >= NIMG * SORTN) return;
    int img = t / SORTN;
    int e = t - img * SORTN;
    if (e >= MTOT) { keys[t] = ~0ULL; return; }
    int lvl = e / TOPK;
    int slot = e - lvl * TOPK;
    int row = lvl * NIMG + img;
    uint32_t bits = outCand[((size_t)row * TOPK + slot) * 2 + 0];
    uint32_t idx = outCand[((size_t)row * TOPK + slot) * 2 + 1];
    uint32_t be = 0;
    if (bits != 0) {
        float bc[4]; int cc; bool ne;
        decode_entry(P, img, lvl, idx, bc, &cc, &ne);
        if (ne) be = bits;
    }
    keys[(size_t)img * SORTN + e] =
        ((uint64_t)(uint32_t)(~be) << 24) | ((uint64_t)lvl << 21) | (uint64_t)idx;
}

// ---- K6: per-image bitonic sort of 8192 keys, fully in LDS ----
__global__ __launch_bounds__(1024) void k_sort(uint64_t* keys) {
    __shared__ uint64_t sk[SORTN];  // 64 KB
    uint64_t* g = keys + (size_t)blockIdx.x * SORTN;
    for (int i = threadIdx.x; i < SORTN; i += 1024) sk[i] = g[i];
    __syncthreads();
    for (int k = 2; k <= SORTN; k <<= 1) {
        for (int j = k >> 1; j > 0; j >>= 1) {
            for (int i = threadIdx.x; i < SORTN; i += 1024) {
                int ixj = i ^ j;
                if (ixj > i) {
                    uint64_t A = sk[i], Bv = sk[ixj];
                    bool up = ((i & k) == 0);
                    if (up ? (A > Bv) : (A < Bv)) { sk[i] = Bv; sk[ixj] = A; }
                }
            }
            __syncthreads();
        }
    }
    for (int i = threadIdx.x; i < SORTN; i += 1024) g[i] = sk[i];
}

// ---- K7: decode sorted entries into NMS-ready arrays ----
__global__ __launch_bounds__(256) void k_prep(Params P, const uint64_t* keys, float4* boff,
                                              float* area, float4* bclip, float* scs, int* clss) {
    int t = blockIdx.x * blockDim.x + threadIdx.x;
    if (t >= NIMG * MTOT) return;
    int img = t / MTOT;
    int e = t - img * MTOT;
    uint64_t k = keys[(size_t)img * SORTN + e];
    uint32_t bits = ~((uint32_t)(k >> 24));
    int lvl = (int)((k >> 21) & 7);
    uint32_t idx = (uint32_t)(k & 0x1FFFFF);
    float bc[4]; int cc; bool ne;
    decode_entry(P, img, lvl, idx, bc, &cc, &ne);
    float sc = 0.0f;
    if (bits != 0) {
        float s = __uint_as_float(bits);
        sc = sqrtf(fmaxf(s, 1e-12f));
    }
    float off = (float)cc * 2000.0f;
    float b0 = bc[0] + off, b1 = bc[1] + off, b2 = bc[2] + off, b3 = bc[3] + off;
    boff[t] = make_float4(b0, b1, b2, b3);
    area[t] = (b2 - b0) * (b3 - b1);
    bclip[t] = make_float4(bc[0], bc[1], bc[2], bc[3]);
    scs[t] = sc;
    clss[t] = cc;
}

// ---- K8: per-image sequential greedy NMS with early exit, write outputs ----
__global__ __launch_bounds__(256) void k_nms(const float4* boff, const float* area,
                                             const float4* bclip, const float* scs,
                                             const int* clss, float* out) {
    int img = blockIdx.x;
    const float4* bo = boff + (size_t)img * MTOT;
    const float* ar = area + (size_t)img * MTOT;
    const float4* bclp = bclip + (size_t)img * MTOT;
    const float* sc = scs + (size_t)img * MTOT;
    const int* cl = clss + (size_t)img * MTOT;
    __shared__ uint32_t sup[(MTOT + 31) / 32 + 1];
    __shared__ int kept[OUTK];
    int tid = threadIdx.x;
    const int NW = (MTOT + 31) / 32;
    for (int w = tid; w < NW; w += 256) {
        uint32_t m = 0;
        for (int b = 0; b < 32; b++) {
            int e = w * 32 + b;
            bool s = (e >= MTOT) || (sc[e] == 0.0f);
            m |= (s ? 1u : 0u) << b;
        }
        sup[w] = m;
    }
    __syncthreads();
    int kc = 0;
    for (int i = 0; i < MTOT; i++) {
        if ((sup[i >> 5] >> (i & 31)) & 1u) continue;
        if (tid == 0) kept[kc] = i;
        float4 bi = bo[i];
        float ai = ar[i];
        for (int j = i + 1 + tid; j < MTOT; j += 256) {
            float4 bj = bo[j];
            float xx1 = fmaxf(bi.x, bj.x), yy1 = fmaxf(bi.y, bj.y);
            float xx2 = fminf(bi.z, bj.z), yy2 = fminf(bi.w, bj.w);
            float inter = fmaxf(xx2 - xx1, 0.0f) * fmaxf(yy2 - yy1, 0.0f);
            float iou = inter / (ai + ar[j] - inter + 1e-9f);
            if (iou > 0.6f) atomicOr(&sup[j >> 5], 1u << (j & 31));
        }
        kc++;
        __syncthreads();
        if (kc == OUTK) break;
    }
    if (tid == 0) {
        int k2 = kc;
        for (int e = 0; e < MTOT && k2 < OUTK; e++) {
            if ((sup[e >> 5] >> (e & 31)) & 1u) kept[k2++] = e | (1 << 30);
        }
    }
    __syncthreads();
    for (int t = tid; t < OUTK; t += 256) {
        int ke = kept[t];
        bool fil = (ke >> 30) & 1;
        int e = ke & 0x3FFFFFFF;
        float4 b = bclp[e];
        out[((size_t)img * OUTK + t) * 4 + 0] = b.x;
        out[((size_t)img * OUTK + t) * 4 + 1] = b.y;
        out[((size_t)img * OUTK + t) * 4 + 2] = b.z;
        out[((size_t)img * OUTK + t) * 4 + 3] = b.w;
        out[NIMG * OUTK * 4 + img * OUTK + t] = fil ? 0.0f : sc[e];
        out[NIMG * OUTK * 4 + NIMG * OUTK + img * OUTK + t] = (float)cl[e];
    }
}

extern "C" void kernel_launch(void* const* d_in, const int* in_sizes, int n_in,
                              void* d_out, int out_size, void* d_ws, size_t ws_size,
                              hipStream_t stream) {
    Params P;
    for (int l = 0; l < 5; l++) {
        P.cls[l] = (const float*)d_in[l * 3 + 0];
        P.reg[l] = (const float*)d_in[l * 3 + 1];
        P.anc[l] = (const float*)d_in[l * 3 + 2];
    }
    P.imsize = (const int*)d_in[15];

    char* w = (char*)d_ws;
    uint32_t* hist     = (uint32_t*)(w + 0);        // 80*288*4      = 92160
    int*      sel      = (int*)(w + 92160);         // 80*4*4        = 1280
    uint32_t* outCount = (uint32_t*)(w + 93440);    // 80*4          = 320
    uint32_t* binBCnt  = (uint32_t*)(w + 93760);    // 80*4          = 320
    uint32_t* outCand  = (uint32_t*)(w + 94080);    // 80*1000*2*4   = 640000 -> 734080
    float*    xth      = (float*)(w + 734080);      // 80*4          = 320
    uint32_t* binB     = (uint32_t*)(w + 734400);   // 80*4096*2*4   = 2621440 -> 3355840
    uint64_t* keys     = (uint64_t*)(w + 3355840);  // 16*8192*8     = 1048576 -> 4404416
    float4*   boff     = (float4*)(w + 4404416);    // 16*5000*16    = 1280000 -> 5684416
    float*    area     = (float*)(w + 5684416);     // 16*5000*4     = 320000  -> 6004416
    float4*   bclipb   = (float4*)(w + 6004416);    // 16*5000*16    = 1280000 -> 7284416
    float*    scs      = (float*)(w + 7284416);     // 16*5000*4     = 320000  -> 7604416
    int*      clss     = (int*)(w + 7604416);       // 16*5000*4     = 320000  -> 7924416

    hipMemsetAsync(w, 0, 734080, stream);  // hist + sel + counters + outCand

    k_hist<<<1632, 256, 0, stream>>>(P, hist);
    k_scan<<<80, 64, 0, stream>>>(hist, sel, xth);
    k_pass2<<<1632, 256, 0, stream>>>(P, sel, xth, outCand, outCount, binB, binBCnt);
    k_selsort<<<80, 256, 0, stream>>>(sel, binB, binBCnt, outCand);
    k_keys<<<(NIMG * SORTN + 255) / 256, 256, 0, stream>>>(P, outCand, keys);
    k_sort<<<NIMG, 1024, 0, stream>>>(keys);
    k_prep<<<(NIMG * MTOT + 255) / 256, 256, 0, stream>>>(P, keys, boff, area, bclipb, scs, clss);
    k_nms<<<NIMG, 256, 0, stream>>>(boff, area, bclipb, scs, clss, (float*)d_out);
}

// Round 3
// 736.010 us; speedup vs baseline: 2.8167x; 1.4883x over previous
//
#include <hip/hip_runtime.h>
#include <stdint.h>
#include <math.h>

#define NLEV 5
#define NIMG 16
#define NCLS 80
#define TOPK 1000
#define MTOT 5000
#define SORTN 8192
#define BINBCAP 4096
#define NBINS 288
#define BIN0 7846
#define OUTK 100
#define CHUNK 16384
#define NMSW 512
#define NMSWORDS 16
#define MW 17

__device__ __constant__ int c_HW[NLEV]   = {15200, 3800, 950, 247, 70};
__device__ __constant__ int c_E[NLEV]    = {1216000, 304000, 76000, 19760, 5600};
__device__ __constant__ int c_cpr[NLEV]  = {75, 19, 5, 2, 1};            // chunks per (img,level) row
__device__ __constant__ int c_cbase[NLEV + 1] = {0, 1200, 1504, 1584, 1616, 1632};

struct Params {
    const float* cls[NLEV];
    const float* reg[NLEV];
    const float* anc[NLEV];
    const int* imsize;
};

// ---- shared decode (must be used identically by k_keys and k_prep) ----
__device__ inline void decode_entry(const Params& P, int img, int lvl, uint32_t idx,
                                    float bclip[4], int* cls_out, bool* nonempty) {
    int HW = c_HW[lvl];
    int loc = (int)idx / NCLS;
    int c = (int)idx - loc * NCLS;
    const float* a = P.anc[lvl] + 4 * loc;
    float a0 = a[0], a1 = a[1], a2 = a[2], a3 = a[3];
    const float* rg = P.reg[lvl] + (size_t)img * 4 * HW + loc;
    float d0 = rg[0], d1 = rg[HW], d2 = rg[2 * HW], d3 = rg[3 * HW];
    float w = a2 - a0 + 1.0f, h = a3 - a1 + 1.0f;
    float cx = a0 + 0.5f * w, cy = a1 + 0.5f * h;
    float dx = d0 / 10.0f, dy = d1 / 10.0f;
    const float SCALE_CLAMP = 4.135166556742356f;
    float dw = fminf(d2 / 5.0f, SCALE_CLAMP);
    float dh = fminf(d3 / 5.0f, SCALE_CLAMP);
    float pcx = dx * w + cx, pcy = dy * h + cy;
    float pw = (float)exp((double)dw) * w;
    float ph = (float)exp((double)dh) * h;
    float x1 = pcx - 0.5f * (pw - 1.0f), y1 = pcy - 0.5f * (ph - 1.0f);
    float x2 = pcx + 0.5f * (pw - 1.0f), y2 = pcy + 0.5f * (ph - 1.0f);
    float Hs = (float)P.imsize[img * 2 + 0];
    float Ws = (float)P.imsize[img * 2 + 1];
    float x1c = fminf(fmaxf(x1, 0.0f), Ws);
    float y1c = fminf(fmaxf(y1, 0.0f), Hs);
    float x2c = fminf(fmaxf(x2, 0.0f), Ws);
    float y2c = fminf(fmaxf(y2, 0.0f), Hs);
    bclip[0] = x1c; bclip[1] = y1c; bclip[2] = x2c; bclip[3] = y2c;
    *cls_out = c;
    *nonempty = ((x2c - x1c) > 0.0f) && ((y2c - y1c) > 0.0f);
}

__device__ inline float sigmoid_f(float x) {
    return (float)(1.0 / (1.0 + exp(-(double)x)));
}

// ordered-uint <-> float (monotone bijection) for threshold bisection
__device__ inline uint32_t f2o(float f) {
    uint32_t b = __float_as_uint(f);
    return (b & 0x80000000u) ? ~b : (b | 0x80000000u);
}
__device__ inline float o2f(uint32_t o) {
    uint32_t b = (o & 0x80000000u) ? (o & 0x7FFFFFFFu) : ~o;
    return __uint_as_float(b);
}

// chunk -> (level, img, element range) mapping shared by k_hist / k_pass2
__device__ inline void chunk_map(int bid, int* lvl, int* img, int* start, int* end) {
    int l = 0;
#pragma unroll
    for (int q = 1; q < NLEV; q++) if (bid >= c_cbase[q]) l = q;
    int r = bid - c_cbase[l];
    int cpr = c_cpr[l];
    int im = r / cpr;
    int ch = r - im * cpr;
    int E = c_E[l];
    int st = ch * CHUNK;
    *lvl = l; *img = im; *start = st; *end = min(st + CHUNK, E);
}

// ---- K1: per-chunk LDS histogram of score bits ----
__global__ __launch_bounds__(256) void k_hist(Params P, uint32_t* hist) {
    __shared__ uint32_t lh[NBINS];
    int l, img, start, end;
    chunk_map(blockIdx.x, &l, &img, &start, &end);
    for (int b = threadIdx.x; b < NBINS; b += 256) lh[b] = 0;
    __syncthreads();
    const float4* p = (const float4*)(P.cls[l] + (size_t)img * c_E[l] + start);
    int n4 = (end - start) >> 2;
    for (int v = threadIdx.x; v < n4; v += 256) {
        float4 x4 = p[v];
        float xs[4] = {x4.x, x4.y, x4.z, x4.w};
#pragma unroll
        for (int k = 0; k < 4; k++) {
            float xv = xs[k];
            if (xv >= -2.95f) {              // sigmoid(-2.95)=0.0497<0.05 -> safe skip
                float s = sigmoid_f(xv);
                if (s > 0.05f) {
                    int bin = (int)(__float_as_uint(s) >> 17) - BIN0;
                    atomicAdd(&lh[bin], 1u);
                }
            }
        }
    }
    __syncthreads();
    int row = l * NIMG + img;
    for (int b = threadIdx.x; b < NBINS; b += 256) {
        uint32_t c = lh[b];
        if (c) atomicAdd(&hist[row * NBINS + b], c);
    }
}

// ---- K2: scan histogram top-down; bisect exact logit threshold per row ----
__global__ void k_scan(const uint32_t* hist, int* sel, float* xth) {
    int row = blockIdx.x;
    if (threadIdx.x != 0) return;
    int cum = 0, B = -1, need = 0, cab = 0;
    for (int b = NBINS - 1; b >= 0; b--) {
        int c = (int)hist[row * NBINS + b];
        if (cum + c >= TOPK) { B = b; cab = cum; need = TOPK - cum; break; }
        cum += c;
    }
    if (B < 0) { cab = cum; need = 0; }
    sel[row * 4 + 0] = B;
    sel[row * 4 + 1] = cab;
    sel[row * 4 + 2] = need;
    sel[row * 4 + 3] = cum;
    // minimal float x with (sigmoid_f(x) > 0.05f && bin >= B); predicate monotone in x
    uint32_t lo = f2o(-4.0f), hi = f2o(20.0f);
    while (hi - lo > 1u) {
        uint32_t mid = lo + ((hi - lo) >> 1);
        float xm = o2f(mid);
        float s = sigmoid_f(xm);
        bool pass = (s > 0.05f) &&
                    (B < 0 || ((int)(__float_as_uint(s) >> 17) - BIN0) >= B);
        if (pass) hi = mid; else lo = mid;
    }
    xth[row] = o2f(hi);
}

// ---- K3: compact candidates (cheap float-compare filter, rare atomics) ----
__global__ __launch_bounds__(256) void k_pass2(Params P, const int* sel, const float* xth,
                                               uint32_t* outCand, uint32_t* outCount,
                                               uint32_t* binB, uint32_t* binBCnt) {
    int l, img, start, end;
    chunk_map(blockIdx.x, &l, &img, &start, &end);
    int row = l * NIMG + img;
    float xt = xth[row];
    int B = sel[row * 4 + 0];
    int HW = c_HW[l];
    const float4* p = (const float4*)(P.cls[l] + (size_t)img * c_E[l] + start);
    int n4 = (end - start) >> 2;
    for (int v = threadIdx.x; v < n4; v += 256) {
        float4 x4 = p[v];
        float xs[4] = {x4.x, x4.y, x4.z, x4.w};
#pragma unroll
        for (int k = 0; k < 4; k++) {
            float xv = xs[k];
            if (xv >= xt) {                       // implies s>0.05f && bin>=B
                float s = sigmoid_f(xv);
                uint32_t bits = __float_as_uint(s);
                int bin = (int)(bits >> 17) - BIN0;
                int q2 = start + v * 4 + k;       // c*HW + p layout
                int c = q2 / HW;
                int pidx = q2 - c * HW;
                uint32_t idx = (uint32_t)(pidx * NCLS + c);
                if (bin > B) {
                    uint32_t pos = atomicAdd(&outCount[row], 1u);
                    if (pos < TOPK) {
                        outCand[((size_t)row * TOPK + pos) * 2 + 0] = bits;
                        outCand[((size_t)row * TOPK + pos) * 2 + 1] = idx;
                    }
                } else {
                    uint32_t p2 = atomicAdd(&binBCnt[row], 1u);
                    if (p2 < BINBCAP) {
                        binB[((size_t)row * BINBCAP + p2) * 2 + 0] = bits;
                        binB[((size_t)row * BINBCAP + p2) * 2 + 1] = idx;
                    }
                }
            }
        }
    }
}

// ---- K4: exact sort of boundary bin, append `need` winners ----
__global__ __launch_bounds__(256) void k_selsort(const int* sel, const uint32_t* binB,
                                                 const uint32_t* binBCnt, uint32_t* outCand) {
    __shared__ uint64_t sk[BINBCAP];
    int row = blockIdx.x;
    int need = sel[row * 4 + 2];
    int cab = sel[row * 4 + 1];
    if (need <= 0) return;
    int cnt = min((int)binBCnt[row], BINBCAP);
    for (int i = threadIdx.x; i < BINBCAP; i += blockDim.x) {
        uint64_t key = ~0ULL;
        if (i < cnt) {
            uint32_t b = binB[((size_t)row * BINBCAP + i) * 2 + 0];
            uint32_t idx = binB[((size_t)row * BINBCAP + i) * 2 + 1];
            key = ((uint64_t)(uint32_t)(~b) << 32) | idx;   // value desc, idx asc
        }
        sk[i] = key;
    }
    __syncthreads();
    for (int k = 2; k <= BINBCAP; k <<= 1) {
        for (int j = k >> 1; j > 0; j >>= 1) {
            for (int i = threadIdx.x; i < BINBCAP; i += blockDim.x) {
                int ixj = i ^ j;
                if (ixj > i) {
                    uint64_t A = sk[i], Bv = sk[ixj];
                    bool up = ((i & k) == 0);
                    if (up ? (A > Bv) : (A < Bv)) { sk[i] = Bv; sk[ixj] = A; }
                }
            }
            __syncthreads();
        }
    }
    int take = min(need, cnt);
    for (int i = threadIdx.x; i < take; i += blockDim.x) {
        uint64_t k = sk[i];
        uint32_t idx = (uint32_t)(k & 0xFFFFFFFFu);
        uint32_t bits = ~((uint32_t)(k >> 32));
        int pos = cab + i;
        outCand[((size_t)row * TOPK + pos) * 2 + 0] = bits;
        outCand[((size_t)row * TOPK + pos) * 2 + 1] = idx;
    }
}

// ---- K5: build 64-bit sort keys (post-nonempty score, ref tie order) ----
__global__ __launch_bounds__(256) void k_keys(Params P, const uint32_t* outCand, uint64_t* keys) {
    int t = blockIdx.x * blockDim.x + threadIdx.x;
    if (t >= NIMG * SORTN) return;
    int img = t / SORTN;
    int e = t - img * SORTN;
    if (e >= MTOT) { keys[t] = ~0ULL; return; }
    int lvl = e / TOPK;
    int slot = e - lvl * TOPK;
    int row = lvl * NIMG + img;
    uint32_t bits = outCand[((size_t)row * TOPK + slot) * 2 + 0];
    uint32_t idx = outCand[((size_t)row * TOPK + slot) * 2 + 1];
    uint32_t be = 0;
    if (bits != 0) {
        float bc[4]; int cc; bool ne;
        decode_entry(P, img, lvl, idx, bc, &cc, &ne);
        if (ne) be = bits;
    }
    keys[(size_t)img * SORTN + e] =
        ((uint64_t)(uint32_t)(~be) << 24) | ((uint64_t)lvl << 21) | (uint64_t)idx;
}

// ---- K6: per-image bitonic sort of 8192 keys, fully in LDS ----
__global__ __launch_bounds__(1024) void k_sort(uint64_t* keys) {
    __shared__ uint64_t sk[SORTN];  // 64 KB
    uint64_t* g = keys + (size_t)blockIdx.x * SORTN;
    for (int i = threadIdx.x; i < SORTN; i += 1024) sk[i] = g[i];
    __syncthreads();
    for (int k = 2; k <= SORTN; k <<= 1) {
        for (int j = k >> 1; j > 0; j >>= 1) {
            for (int i = threadIdx.x; i < SORTN; i += 1024) {
                int ixj = i ^ j;
                if (ixj > i) {
                    uint64_t A = sk[i], Bv = sk[ixj];
                    bool up = ((i & k) == 0);
                    if (up ? (A > Bv) : (A < Bv)) { sk[i] = Bv; sk[ixj] = A; }
                }
            }
            __syncthreads();
        }
    }
    for (int i = threadIdx.x; i < SORTN; i += 1024) g[i] = sk[i];
}

// ---- K7: decode sorted entries into NMS-ready arrays ----
__global__ __launch_bounds__(256) void k_prep(Params P, const uint64_t* keys, float4* boff,
                                              float* area, float4* bclip, float* scs, int* clss) {
    int t = blockIdx.x * blockDim.x + threadIdx.x;
    if (t >= NIMG * MTOT) return;
    int img = t / MTOT;
    int e = t - img * MTOT;
    uint64_t k = keys[(size_t)img * SORTN + e];
    uint32_t bits = ~((uint32_t)(k >> 24));
    int lvl = (int)((k >> 21) & 7);
    uint32_t idx = (uint32_t)(k & 0x1FFFFF);
    float bc[4]; int cc; bool ne;
    decode_entry(P, img, lvl, idx, bc, &cc, &ne);
    float sc = 0.0f;
    if (bits != 0) {
        float s = __uint_as_float(bits);
        sc = sqrtf(fmaxf(s, 1e-12f));
    }
    float off = (float)cc * 2000.0f;
    float b0 = bc[0] + off, b1 = bc[1] + off, b2 = bc[2] + off, b3 = bc[3] + off;
    boff[t] = make_float4(b0, b1, b2, b3);
    area[t] = (b2 - b0) * (b3 - b1);
    bclip[t] = make_float4(bc[0], bc[1], bc[2], bc[3]);
    scs[t] = sc;
    clss[t] = cc;
}

// ---- K8: windowed exact greedy NMS (bit-matrix + wave-lockstep scan) ----
__global__ __launch_bounds__(256) void k_nms(const float4* boff, const float* area,
                                             const float4* bclip, const float* scs,
                                             const int* clss, float* out) {
    int img = blockIdx.x;
    const float4* bo = boff + (size_t)img * MTOT;
    const float* ar = area + (size_t)img * MTOT;
    const float4* bclp = bclip + (size_t)img * MTOT;
    const float* sc = scs + (size_t)img * MTOT;
    const int* cl = clss + (size_t)img * MTOT;

    __shared__ float sx1[NMSW], sy1[NMSW], sx2[NMSW], sy2[NMSW], sar[NMSW], ssc[NMSW];
    __shared__ uint32_t mask[NMSW * MW];    // row-padded: stride 17 coprime with 32 banks
    __shared__ uint32_t presup[NMSWORDS];
    __shared__ uint32_t gsup[160];          // final suppression bits (filler path)
    __shared__ float kx1[OUTK], ky1[OUTK], kx2[OUTK], ky2[OUTK], kar[OUTK];
    __shared__ int keptIdx[OUTK];
    __shared__ int s_kc, s_done;

    int tid = threadIdx.x;
    if (tid == 0) { s_kc = 0; s_done = 0; }
    __syncthreads();

    for (int wstart = 0; wstart < MTOT; wstart += NMSW) {
        int L = min(NMSW, MTOT - wstart);
        // ---- load window (SoA) ----
        for (int j = tid; j < NMSW; j += 256) {
            if (j < L) {
                float4 b = bo[wstart + j];
                sx1[j] = b.x; sy1[j] = b.y; sx2[j] = b.z; sy2[j] = b.w;
                sar[j] = ar[wstart + j];
                ssc[j] = sc[wstart + j];
            } else {
                ssc[j] = 0.0f;
            }
        }
        __syncthreads();
        int kc0 = s_kc;
        // ---- presup words: invalid (score 0) or out of range ----
        if (tid < NMSWORDS) {
            uint32_t m = 0;
            for (int b = 0; b < 32; b++) {
                int j = tid * 32 + b;
                if (j >= L || ssc[j] == 0.0f) m |= 1u << b;
            }
            presup[tid] = m;
        }
        __syncthreads();
        // ---- pre-suppress by kept boxes from earlier windows (rare path) ----
        if (kc0 > 0) {
            for (int j = tid; j < L; j += 256) {
                if (ssc[j] == 0.0f) continue;
                float bx1 = sx1[j], by1 = sy1[j], bx2 = sx2[j], by2 = sy2[j], baj = sar[j];
                bool supd = false;
                for (int k = 0; k < kc0; k++) {
                    float xx1 = fmaxf(kx1[k], bx1), yy1 = fmaxf(ky1[k], by1);
                    float xx2 = fminf(kx2[k], bx2), yy2 = fminf(ky2[k], by2);
                    float inter = fmaxf(xx2 - xx1, 0.0f) * fmaxf(yy2 - yy1, 0.0f);
                    float iou = inter / (kar[k] + baj - inter + 1e-9f);
                    if (iou > 0.6f) supd = true;
                }
                if (supd) atomicOr(&presup[j >> 5], 1u << (j & 31));
            }
            __syncthreads();
        }
        // ---- build in-window suppression bit matrix (j > i) ----
        for (int i = tid; i < NMSW; i += 256) {
            if (i < L) {
                float bx1 = sx1[i], by1 = sy1[i], bx2 = sx2[i], by2 = sy2[i], bai = sar[i];
                for (int w = 0; w < NMSWORDS; w++) {
                    uint32_t m = 0;
                    int j0 = max(w * 32, i + 1);
                    int j1 = min(w * 32 + 32, L);
                    for (int j = j0; j < j1; j++) {
                        float xx1 = fmaxf(bx1, sx1[j]), yy1 = fmaxf(by1, sy1[j]);
                        float xx2 = fminf(bx2, sx2[j]), yy2 = fminf(by2, sy2[j]);
                        float inter = fmaxf(xx2 - xx1, 0.0f) * fmaxf(yy2 - yy1, 0.0f);
                        float iou = inter / (bai + sar[j] - inter + 1e-9f);
                        if (iou > 0.6f) m |= 1u << (j - w * 32);
                    }
                    mask[i * MW + w] = m;
                }
            }
        }
        __syncthreads();
        // ---- serial greedy scan: single wave, lockstep, state in lane registers ----
        if (tid < 64) {
            int lane = tid;
            uint32_t supw = (lane < NMSWORDS) ? presup[lane] : 0xFFFFFFFFu;
            int kc = kc0;
            for (int i = 0; i < L; i++) {
                uint32_t wv = __shfl(supw, i >> 5);
                if (!((wv >> (i & 31)) & 1u)) {
                    if (lane == 0) {
                        keptIdx[kc] = wstart + i;
                        kx1[kc] = sx1[i]; ky1[kc] = sy1[i];
                        kx2[kc] = sx2[i]; ky2[kc] = sy2[i];
                        kar[kc] = sar[i];
                    }
                    if (lane < NMSWORDS) supw |= mask[i * MW + lane];
                    kc++;
                    if (kc == OUTK) { if (lane == 0) { s_kc = kc; s_done = 1; } break; }
                }
            }
            if (lane == 0 && s_done == 0) s_kc = kc;
            if (lane < NMSWORDS) gsup[(wstart >> 5) + lane] = supw;
        }
        __syncthreads();
        if (s_done) break;
    }

    // ---- filler: first suppressed/invalid entries, index order (score 0) ----
    int kc = s_kc;
    if (tid == 0 && kc < OUTK) {
        int k2 = kc;
        for (int e = 0; e < MTOT && k2 < OUTK; e++) {
            if ((gsup[e >> 5] >> (e & 31)) & 1u) keptIdx[k2++] = e | (1 << 30);
        }
    }
    __syncthreads();

    for (int t = tid; t < OUTK; t += 256) {
        int ke = keptIdx[t];
        bool fil = (ke >> 30) & 1;
        int e = ke & 0x3FFFFFFF;
        float4 b = bclp[e];
        out[((size_t)img * OUTK + t) * 4 + 0] = b.x;
        out[((size_t)img * OUTK + t) * 4 + 1] = b.y;
        out[((size_t)img * OUTK + t) * 4 + 2] = b.z;
        out[((size_t)img * OUTK + t) * 4 + 3] = b.w;
        out[NIMG * OUTK * 4 + img * OUTK + t] = fil ? 0.0f : sc[e];
        out[NIMG * OUTK * 4 + NIMG * OUTK + img * OUTK + t] = (float)cl[e];
    }
}

extern "C" void kernel_launch(void* const* d_in, const int* in_sizes, int n_in,
                              void* d_out, int out_size, void* d_ws, size_t ws_size,
                              hipStream_t stream) {
    Params P;
    for (int l = 0; l < 5; l++) {
        P.cls[l] = (const float*)d_in[l * 3 + 0];
        P.reg[l] = (const float*)d_in[l * 3 + 1];
        P.anc[l] = (const float*)d_in[l * 3 + 2];
    }
    P.imsize = (const int*)d_in[15];

    char* w = (char*)d_ws;
    uint32_t* hist     = (uint32_t*)(w + 0);        // 80*288*4      = 92160
    int*      sel      = (int*)(w + 92160);         // 80*4*4        = 1280
    uint32_t* outCount = (uint32_t*)(w + 93440);    // 80*4          = 320
    uint32_t* binBCnt  = (uint32_t*)(w + 93760);    // 80*4          = 320
    uint32_t* outCand  = (uint32_t*)(w + 94080);    // 80*1000*2*4   = 640000 -> 734080
    float*    xth      = (float*)(w + 734080);      // 80*4          = 320
    uint32_t* binB     = (uint32_t*)(w + 734400);   // 80*4096*2*4   = 2621440 -> 3355840
    uint64_t* keys     = (uint64_t*)(w + 3355840);  // 16*8192*8     = 1048576 -> 4404416
    float4*   boff     = (float4*)(w + 4404416);    // 16*5000*16    = 1280000 -> 5684416
    float*    area     = (float*)(w + 5684416);     // 16*5000*4     = 320000  -> 6004416
    float4*   bclipb   = (float4*)(w + 6004416);    // 16*5000*16    = 1280000 -> 7284416
    float*    scs      = (float*)(w + 7284416);     // 16*5000*4     = 320000  -> 7604416
    int*      clss     = (int*)(w + 7604416);       // 16*5000*4     = 320000  -> 7924416

    hipMemsetAsync(w, 0, 734080, stream);  // hist + sel + counters + outCand

    k_hist<<<1632, 256, 0, stream>>>(P, hist);
    k_scan<<<80, 64, 0, stream>>>(hist, sel, xth);
    k_pass2<<<1632, 256, 0, stream>>>(P, sel, xth, outCand, outCount, binB, binBCnt);
    k_selsort<<<80, 256, 0, stream>>>(sel, binB, binBCnt, outCand);
    k_keys<<<(NIMG * SORTN + 255) / 256, 256, 0, stream>>>(P, outCand, keys);
    k_sort<<<NIMG, 1024, 0, stream>>>(keys);
    k_prep<<<(NIMG * MTOT + 255) / 256, 256, 0, stream>>>(P, keys, boff, area, bclipb, scs, clss);
    k_nms<<<NIMG, 256, 0, stream>>>(boff, area, bclipb, scs, clss, (float*)d_out);
}

// Round 4
// 533.659 us; speedup vs baseline: 3.8848x; 1.3792x over previous
//
#include <hip/hip_runtime.h>
#include <stdint.h>
#include <math.h>

#define NLEV 5
#define NIMG 16
#define NCLS 80
#define TOPK 1000
#define MTOT 5000
#define SORTN 8192
#define BINBCAP 4096
#define NBINS 288
#define BIN0 7846
#define OUTK 100
#define CHUNK 16384
#define NCHUNK 1632
#define NMSW 512
#define NMSWORDS 16
#define MW 17
#define PCAP_MAIN 1024
#define PCAP_BND 2048

__device__ __constant__ int c_HW[NLEV]   = {15200, 3800, 950, 247, 70};
__device__ __constant__ int c_E[NLEV]    = {1216000, 304000, 76000, 19760, 5600};
__device__ __constant__ int c_cpr[NLEV]  = {75, 19, 5, 2, 1};            // chunks per (img,level) row
__device__ __constant__ int c_cbase[NLEV + 1] = {0, 1200, 1504, 1584, 1616, 1632};

struct Params {
    const float* cls[NLEV];
    const float* reg[NLEV];
    const float* anc[NLEV];
    const int* imsize;
};

// ---- shared decode (must be used identically by k_keys and k_prep) ----
__device__ inline void decode_entry(const Params& P, int img, int lvl, uint32_t idx,
                                    float bclip[4], int* cls_out, bool* nonempty) {
    int HW = c_HW[lvl];
    int loc = (int)idx / NCLS;
    int c = (int)idx - loc * NCLS;
    const float* a = P.anc[lvl] + 4 * loc;
    float a0 = a[0], a1 = a[1], a2 = a[2], a3 = a[3];
    const float* rg = P.reg[lvl] + (size_t)img * 4 * HW + loc;
    float d0 = rg[0], d1 = rg[HW], d2 = rg[2 * HW], d3 = rg[3 * HW];
    float w = a2 - a0 + 1.0f, h = a3 - a1 + 1.0f;
    float cx = a0 + 0.5f * w, cy = a1 + 0.5f * h;
    float dx = d0 / 10.0f, dy = d1 / 10.0f;
    const float SCALE_CLAMP = 4.135166556742356f;
    float dw = fminf(d2 / 5.0f, SCALE_CLAMP);
    float dh = fminf(d3 / 5.0f, SCALE_CLAMP);
    float pcx = dx * w + cx, pcy = dy * h + cy;
    float pw = (float)exp((double)dw) * w;
    float ph = (float)exp((double)dh) * h;
    float x1 = pcx - 0.5f * (pw - 1.0f), y1 = pcy - 0.5f * (ph - 1.0f);
    float x2 = pcx + 0.5f * (pw - 1.0f), y2 = pcy + 0.5f * (ph - 1.0f);
    float Hs = (float)P.imsize[img * 2 + 0];
    float Ws = (float)P.imsize[img * 2 + 1];
    float x1c = fminf(fmaxf(x1, 0.0f), Ws);
    float y1c = fminf(fmaxf(y1, 0.0f), Hs);
    float x2c = fminf(fmaxf(x2, 0.0f), Ws);
    float y2c = fminf(fmaxf(y2, 0.0f), Hs);
    bclip[0] = x1c; bclip[1] = y1c; bclip[2] = x2c; bclip[3] = y2c;
    *cls_out = c;
    *nonempty = ((x2c - x1c) > 0.0f) && ((y2c - y1c) > 0.0f);
}

__device__ inline float sigmoid_f(float x) {
    return (float)(1.0 / (1.0 + exp(-(double)x)));
}

// ordered-uint <-> float (monotone bijection) for threshold bisection
__device__ inline uint32_t f2o(float f) {
    uint32_t b = __float_as_uint(f);
    return (b & 0x80000000u) ? ~b : (b | 0x80000000u);
}
__device__ inline float o2f(uint32_t o) {
    uint32_t b = (o & 0x80000000u) ? (o & 0x7FFFFFFFu) : ~o;
    return __uint_as_float(b);
}

// chunk -> (level, img, element range) mapping shared by k_hist / k_pass2
__device__ inline void chunk_map(int bid, int* lvl, int* img, int* start, int* end) {
    int l = 0;
#pragma unroll
    for (int q = 1; q < NLEV; q++) if (bid >= c_cbase[q]) l = q;
    int r = bid - c_cbase[l];
    int cpr = c_cpr[l];
    int im = r / cpr;
    int ch = r - im * cpr;
    int E = c_E[l];
    int st = ch * CHUNK;
    *lvl = l; *img = im; *start = st; *end = min(st + CHUNK, E);
}

// ---- K0: per-bin minimal-logit thresholds T[b] (monotone bisection) ----
__global__ void k_thr(float* T) {
    int b = blockIdx.x * blockDim.x + threadIdx.x;
    if (b >= NBINS) return;
    uint32_t lo = f2o(-4.0f), hi = f2o(20.0f);
    while (hi - lo > 1u) {
        uint32_t mid = lo + ((hi - lo) >> 1);
        float xm = o2f(mid);
        float s = sigmoid_f(xm);
        bool pass = (s > 0.05f) && (((int)(__float_as_uint(s) >> 17) - BIN0) >= b);
        if (pass) hi = mid; else lo = mid;
    }
    float xr = o2f(hi);
    // bins never reachable (s<1 -> bin<=282): mark +INF so binary search skips them
    float sv = sigmoid_f(xr);
    bool ok = (sv > 0.05f) && (((int)(__float_as_uint(sv) >> 17) - BIN0) >= b);
    T[b] = ok ? xr : __uint_as_float(0x7F800000u);
}

// ---- K1: per-chunk private histogram via threshold-table binary search ----
__global__ __launch_bounds__(256) void k_hist(Params P, const float* T, uint32_t* histB) {
    __shared__ uint32_t lh[NBINS];
    __shared__ float sT[NBINS];
    int l, img, start, end;
    chunk_map(blockIdx.x, &l, &img, &start, &end);
    for (int b = threadIdx.x; b < NBINS; b += 256) { lh[b] = 0; sT[b] = T[b]; }
    __syncthreads();
    float t0 = sT[0];
    const float4* p = (const float4*)(P.cls[l] + (size_t)img * c_E[l] + start);
    int n4 = (end - start) >> 2;
    for (int v = threadIdx.x; v < n4; v += 256) {
        float4 x4 = p[v];
        float xs[4] = {x4.x, x4.y, x4.z, x4.w};
#pragma unroll
        for (int k = 0; k < 4; k++) {
            float xv = xs[k];
            if (xv >= t0) {
                int lo = 0, hi = NBINS;           // x >= sT[lo], x < sT[hi]
                while (hi - lo > 1) {
                    int mid = (lo + hi) >> 1;
                    if (xv >= sT[mid]) lo = mid; else hi = mid;
                }
                atomicAdd(&lh[lo], 1u);
            }
        }
    }
    __syncthreads();
    uint32_t* hb = histB + (size_t)blockIdx.x * NBINS;
    for (int b = threadIdx.x; b < NBINS; b += 256) hb[b] = lh[b];
}

// ---- K2: reduce per-chunk histograms, scan top-down for boundary bin ----
__global__ __launch_bounds__(256) void k_scan(const uint32_t* histB, int* sel) {
    __shared__ uint32_t lh[NBINS];
    int row = blockIdx.x;
    int l = row / NIMG, img = row - l * NIMG;
    int cb = c_cbase[l] + img * c_cpr[l];
    int nc = c_cpr[l];
    for (int b = threadIdx.x; b < NBINS; b += 256) {
        uint32_t s = 0;
        for (int c = 0; c < nc; c++) s += histB[(size_t)(cb + c) * NBINS + b];
        lh[b] = s;
    }
    __syncthreads();
    if (threadIdx.x == 0) {
        int cum = 0, B = -1, need = 0, cab = 0;
        for (int b = NBINS - 1; b >= 0; b--) {
            int c = (int)lh[b];
            if (cum + c >= TOPK) { B = b; cab = cum; need = TOPK - cum; break; }
            cum += c;
        }
        if (B < 0) { cab = cum; need = 0; }
        sel[row * 4 + 0] = B;
        sel[row * 4 + 1] = cab;
        sel[row * 4 + 2] = need;
        sel[row * 4 + 3] = cum;
    }
}

// ---- K3: compact candidates; LDS-privatized, one range-reserve per block ----
__global__ __launch_bounds__(256) void k_pass2(Params P, const int* sel, const float* T,
                                               uint32_t* outCand, uint32_t* outCount,
                                               uint32_t* binB, uint32_t* binBCnt) {
    __shared__ uint64_t smain[PCAP_MAIN];
    __shared__ uint64_t sbnd[PCAP_BND];
    __shared__ uint32_t cnt2[2];
    __shared__ uint32_t base2[2];
    int l, img, start, end;
    chunk_map(blockIdx.x, &l, &img, &start, &end);
    int row = l * NIMG + img;
    int B = sel[row * 4 + 0];
    float xt = T[max(B, 0)];
    int HW = c_HW[l];
    if (threadIdx.x < 2) cnt2[threadIdx.x] = 0;
    __syncthreads();
    const float4* p = (const float4*)(P.cls[l] + (size_t)img * c_E[l] + start);
    int n4 = (end - start) >> 2;
    for (int v = threadIdx.x; v < n4; v += 256) {
        float4 x4 = p[v];
        float xs[4] = {x4.x, x4.y, x4.z, x4.w};
#pragma unroll
        for (int k = 0; k < 4; k++) {
            float xv = xs[k];
            if (xv >= xt) {                       // implies s>0.05f && bin>=B
                float s = sigmoid_f(xv);
                uint32_t bits = __float_as_uint(s);
                int bin = (int)(bits >> 17) - BIN0;
                int q2 = start + v * 4 + k;       // c*HW + p layout
                int c = q2 / HW;
                int pidx = q2 - c * HW;
                uint32_t idx = (uint32_t)(pidx * NCLS + c);
                uint64_t rec = ((uint64_t)bits << 32) | idx;
                if (bin > B) {
                    uint32_t lp = atomicAdd(&cnt2[0], 1u);
                    if (lp < PCAP_MAIN) smain[lp] = rec;   // cab<=999 -> never overflows
                    else {
                        uint32_t pos = atomicAdd(&outCount[row], 1u);
                        if (pos < TOPK)
                            ((uint2*)outCand)[(size_t)row * TOPK + pos] = make_uint2(bits, idx);
                    }
                } else {
                    uint32_t lp = atomicAdd(&cnt2[1], 1u);
                    if (lp < PCAP_BND) sbnd[lp] = rec;
                    else {
                        uint32_t p2 = atomicAdd(&binBCnt[row], 1u);
                        if (p2 < BINBCAP)
                            ((uint2*)binB)[(size_t)row * BINBCAP + p2] = make_uint2(bits, idx);
                    }
                }
            }
        }
    }
    __syncthreads();
    if (threadIdx.x == 0) base2[0] = atomicAdd(&outCount[row], min(cnt2[0], (uint32_t)PCAP_MAIN));
    if (threadIdx.x == 1) base2[1] = atomicAdd(&binBCnt[row], min(cnt2[1], (uint32_t)PCAP_BND));
    __syncthreads();
    uint32_t n0 = min(cnt2[0], (uint32_t)PCAP_MAIN);
    for (uint32_t i = threadIdx.x; i < n0; i += 256) {
        uint32_t pos = base2[0] + i;
        if (pos < TOPK) {
            uint64_t r = smain[i];
            ((uint2*)outCand)[(size_t)row * TOPK + pos] = make_uint2((uint32_t)(r >> 32), (uint32_t)r);
        }
    }
    uint32_t n1 = min(cnt2[1], (uint32_t)PCAP_BND);
    for (uint32_t i = threadIdx.x; i < n1; i += 256) {
        uint32_t pos = base2[1] + i;
        if (pos < BINBCAP) {
            uint64_t r = sbnd[i];
            ((uint2*)binB)[(size_t)row * BINBCAP + pos] = make_uint2((uint32_t)(r >> 32), (uint32_t)r);
        }
    }
}

// ---- K4: exact sort of boundary bin, append `need` winners ----
__global__ __launch_bounds__(256) void k_selsort(const int* sel, const uint32_t* binB,
                                                 const uint32_t* binBCnt, uint32_t* outCand) {
    __shared__ uint64_t sk[BINBCAP];
    int row = blockIdx.x;
    int need = sel[row * 4 + 2];
    int cab = sel[row * 4 + 1];
    if (need <= 0) return;
    int cnt = min((int)binBCnt[row], BINBCAP);
    for (int i = threadIdx.x; i < BINBCAP; i += blockDim.x) {
        uint64_t key = ~0ULL;
        if (i < cnt) {
            uint32_t b = binB[((size_t)row * BINBCAP + i) * 2 + 0];
            uint32_t idx = binB[((size_t)row * BINBCAP + i) * 2 + 1];
            key = ((uint64_t)(uint32_t)(~b) << 32) | idx;   // value desc, idx asc
        }
        sk[i] = key;
    }
    __syncthreads();
    for (int k = 2; k <= BINBCAP; k <<= 1) {
        for (int j = k >> 1; j > 0; j >>= 1) {
            for (int i = threadIdx.x; i < BINBCAP; i += blockDim.x) {
                int ixj = i ^ j;
                if (ixj > i) {
                    uint64_t A = sk[i], Bv = sk[ixj];
                    bool up = ((i & k) == 0);
                    if (up ? (A > Bv) : (A < Bv)) { sk[i] = Bv; sk[ixj] = A; }
                }
            }
            __syncthreads();
        }
    }
    int take = min(need, cnt);
    for (int i = threadIdx.x; i < take; i += blockDim.x) {
        uint64_t k = sk[i];
        uint32_t idx = (uint32_t)(k & 0xFFFFFFFFu);
        uint32_t bits = ~((uint32_t)(k >> 32));
        int pos = cab + i;
        outCand[((size_t)row * TOPK + pos) * 2 + 0] = bits;
        outCand[((size_t)row * TOPK + pos) * 2 + 1] = idx;
    }
}

// ---- K5: build 64-bit sort keys (post-nonempty score, ref tie order) ----
__global__ __launch_bounds__(256) void k_keys(Params P, const uint32_t* outCand,
                                              const int* sel, const uint32_t* binBCnt,
                                              uint64_t* keys) {
    int t = blockIdx.x * blockDim.x + threadIdx.x;
    if (t >= NIMG * SORTN) return;
    int img = t / SORTN;
    int e = t - img * SORTN;
    if (e >= MTOT) { keys[t] = ~0ULL; return; }
    int lvl = e / TOPK;
    int slot = e - lvl * TOPK;
    int row = lvl * NIMG + img;
    int Bq = sel[row * 4 + 0], cab = sel[row * 4 + 1];
    int need = sel[row * 4 + 2], cum = sel[row * 4 + 3];
    int cnt = min((int)binBCnt[row], BINBCAP);
    int filled = (Bq < 0) ? cum : (cab + min(need, cnt));
    uint32_t bits = 0, idx = 0;
    if (slot < filled) {
        uint2 r = ((const uint2*)outCand)[(size_t)row * TOPK + slot];
        bits = r.x; idx = r.y;
    }
    uint32_t be = 0;
    if (bits != 0) {
        float bc[4]; int cc; bool ne;
        decode_entry(P, img, lvl, idx, bc, &cc, &ne);
        if (ne) be = bits;
    }
    keys[(size_t)img * SORTN + e] =
        ((uint64_t)(uint32_t)(~be) << 24) | ((uint64_t)lvl << 21) | (uint64_t)idx;
}

// ---- K6: per-image bitonic sort of 8192 keys, fully in LDS ----
__global__ __launch_bounds__(1024) void k_sort(uint64_t* keys) {
    __shared__ uint64_t sk[SORTN];  // 64 KB
    uint64_t* g = keys + (size_t)blockIdx.x * SORTN;
    for (int i = threadIdx.x; i < SORTN; i += 1024) sk[i] = g[i];
    __syncthreads();
    for (int k = 2; k <= SORTN; k <<= 1) {
        for (int j = k >> 1; j > 0; j >>= 1) {
            for (int i = threadIdx.x; i < SORTN; i += 1024) {
                int ixj = i ^ j;
                if (ixj > i) {
                    uint64_t A = sk[i], Bv = sk[ixj];
                    bool up = ((i & k) == 0);
                    if (up ? (A > Bv) : (A < Bv)) { sk[i] = Bv; sk[ixj] = A; }
                }
            }
            __syncthreads();
        }
    }
    for (int i = threadIdx.x; i < SORTN; i += 1024) g[i] = sk[i];
}

// ---- K7: decode sorted entries into NMS-ready arrays ----
__global__ __launch_bounds__(256) void k_prep(Params P, const uint64_t* keys, float4* boff,
                                              float* area, float4* bclip, float* scs, int* clss) {
    int t = blockIdx.x * blockDim.x + threadIdx.x;
    if (t >= NIMG * MTOT) return;
    int img = t / MTOT;
    int e = t - img * MTOT;
    uint64_t k = keys[(size_t)img * SORTN + e];
    uint32_t bits = ~((uint32_t)(k >> 24));
    int lvl = (int)((k >> 21) & 7);
    uint32_t idx = (uint32_t)(k & 0x1FFFFF);
    float bc[4]; int cc; bool ne;
    decode_entry(P, img, lvl, idx, bc, &cc, &ne);
    float sc = 0.0f;
    if (bits != 0) {
        float s = __uint_as_float(bits);
        sc = sqrtf(fmaxf(s, 1e-12f));
    }
    float off = (float)cc * 2000.0f;
    float b0 = bc[0] + off, b1 = bc[1] + off, b2 = bc[2] + off, b3 = bc[3] + off;
    boff[t] = make_float4(b0, b1, b2, b3);
    area[t] = (b2 - b0) * (b3 - b1);
    bclip[t] = make_float4(bc[0], bc[1], bc[2], bc[3]);
    scs[t] = sc;
    clss[t] = cc;
}

// ---- K8: windowed exact greedy NMS (bit-matrix + wave-lockstep scan) ----
__global__ __launch_bounds__(256) void k_nms(const float4* boff, const float* area,
                                             const float4* bclip, const float* scs,
                                             const int* clss, float* out) {
    int img = blockIdx.x;
    const float4* bo = boff + (size_t)img * MTOT;
    const float* ar = area + (size_t)img * MTOT;
    const float4* bclp = bclip + (size_t)img * MTOT;
    const float* sc = scs + (size_t)img * MTOT;
    const int* cl = clss + (size_t)img * MTOT;

    __shared__ float sx1[NMSW], sy1[NMSW], sx2[NMSW], sy2[NMSW], sar[NMSW], ssc[NMSW];
    __shared__ uint32_t mask[NMSW * MW];    // row-padded: stride 17 coprime with 32 banks
    __shared__ uint32_t presup[NMSWORDS];
    __shared__ uint32_t gsup[160];          // final suppression bits (filler path)
    __shared__ float kx1[OUTK], ky1[OUTK], kx2[OUTK], ky2[OUTK], kar[OUTK];
    __shared__ int keptIdx[OUTK];
    __shared__ int s_kc, s_done;

    int tid = threadIdx.x;
    if (tid == 0) { s_kc = 0; s_done = 0; }
    __syncthreads();

    for (int wstart = 0; wstart < MTOT; wstart += NMSW) {
        int L = min(NMSW, MTOT - wstart);
        for (int j = tid; j < NMSW; j += 256) {
            if (j < L) {
                float4 b = bo[wstart + j];
                sx1[j] = b.x; sy1[j] = b.y; sx2[j] = b.z; sy2[j] = b.w;
                sar[j] = ar[wstart + j];
                ssc[j] = sc[wstart + j];
            } else {
                ssc[j] = 0.0f;
            }
        }
        __syncthreads();
        int kc0 = s_kc;
        if (tid < NMSWORDS) {
            uint32_t m = 0;
            for (int b = 0; b < 32; b++) {
                int j = tid * 32 + b;
                if (j >= L || ssc[j] == 0.0f) m |= 1u << b;
            }
            presup[tid] = m;
        }
        __syncthreads();
        if (kc0 > 0) {
            for (int j = tid; j < L; j += 256) {
                if (ssc[j] == 0.0f) continue;
                float bx1 = sx1[j], by1 = sy1[j], bx2 = sx2[j], by2 = sy2[j], baj = sar[j];
                bool supd = false;
                for (int k = 0; k < kc0; k++) {
                    float xx1 = fmaxf(kx1[k], bx1), yy1 = fmaxf(ky1[k], by1);
                    float xx2 = fminf(kx2[k], bx2), yy2 = fminf(ky2[k], by2);
                    float inter = fmaxf(xx2 - xx1, 0.0f) * fmaxf(yy2 - yy1, 0.0f);
                    float iou = inter / (kar[k] + baj - inter + 1e-9f);
                    if (iou > 0.6f) supd = true;
                }
                if (supd) atomicOr(&presup[j >> 5], 1u << (j & 31));
            }
            __syncthreads();
        }
        for (int i = tid; i < NMSW; i += 256) {
            if (i < L) {
                float bx1 = sx1[i], by1 = sy1[i], bx2 = sx2[i], by2 = sy2[i], bai = sar[i];
                for (int w = 0; w < NMSWORDS; w++) {
                    uint32_t m = 0;
                    int j0 = max(w * 32, i + 1);
                    int j1 = min(w * 32 + 32, L);
                    for (int j = j0; j < j1; j++) {
                        float xx1 = fmaxf(bx1, sx1[j]), yy1 = fmaxf(by1, sy1[j]);
                        float xx2 = fminf(bx2, sx2[j]), yy2 = fminf(by2, sy2[j]);
                        float inter = fmaxf(xx2 - xx1, 0.0f) * fmaxf(yy2 - yy1, 0.0f);
                        float iou = inter / (bai + sar[j] - inter + 1e-9f);
                        if (iou > 0.6f) m |= 1u << (j - w * 32);
                    }
                    mask[i * MW + w] = m;
                }
            }
        }
        __syncthreads();
        if (tid < 64) {
            int lane = tid;
            uint32_t supw = (lane < NMSWORDS) ? presup[lane] : 0xFFFFFFFFu;
            int kc = kc0;
            for (int i = 0; i < L; i++) {
                uint32_t wv = __shfl(supw, i >> 5);
                if (!((wv >> (i & 31)) & 1u)) {
                    if (lane == 0) {
                        keptIdx[kc] = wstart + i;
                        kx1[kc] = sx1[i]; ky1[kc] = sy1[i];
                        kx2[kc] = sx2[i]; ky2[kc] = sy2[i];
                        kar[kc] = sar[i];
                    }
                    if (lane < NMSWORDS) supw |= mask[i * MW + lane];
                    kc++;
                    if (kc == OUTK) { if (lane == 0) { s_kc = kc; s_done = 1; } break; }
                }
            }
            if (lane == 0 && s_done == 0) s_kc = kc;
            if (lane < NMSWORDS) gsup[(wstart >> 5) + lane] = supw;
        }
        __syncthreads();
        if (s_done) break;
    }

    int kc = s_kc;
    if (tid == 0 && kc < OUTK) {
        int k2 = kc;
        for (int e = 0; e < MTOT && k2 < OUTK; e++) {
            if ((gsup[e >> 5] >> (e & 31)) & 1u) keptIdx[k2++] = e | (1 << 30);
        }
    }
    __syncthreads();

    for (int t = tid; t < OUTK; t += 256) {
        int ke = keptIdx[t];
        bool fil = (ke >> 30) & 1;
        int e = ke & 0x3FFFFFFF;
        float4 b = bclp[e];
        out[((size_t)img * OUTK + t) * 4 + 0] = b.x;
        out[((size_t)img * OUTK + t) * 4 + 1] = b.y;
        out[((size_t)img * OUTK + t) * 4 + 2] = b.z;
        out[((size_t)img * OUTK + t) * 4 + 3] = b.w;
        out[NIMG * OUTK * 4 + img * OUTK + t] = fil ? 0.0f : sc[e];
        out[NIMG * OUTK * 4 + NIMG * OUTK + img * OUTK + t] = (float)cl[e];
    }
}

extern "C" void kernel_launch(void* const* d_in, const int* in_sizes, int n_in,
                              void* d_out, int out_size, void* d_ws, size_t ws_size,
                              hipStream_t stream) {
    Params P;
    for (int l = 0; l < 5; l++) {
        P.cls[l] = (const float*)d_in[l * 3 + 0];
        P.reg[l] = (const float*)d_in[l * 3 + 1];
        P.anc[l] = (const float*)d_in[l * 3 + 2];
    }
    P.imsize = (const int*)d_in[15];

    char* w = (char*)d_ws;
    // Lifetime-aliased layout (total 4,568,576 bytes):
    //   regionA [0 .. 2621440): histB (k_hist->k_scan) | binB (k_pass2->k_selsort)
    //                           | boff/area/part of bclip (k_prep->k_nms)
    uint32_t* histB    = (uint32_t*)(w + 0);        // 1632*288*4 = 1880064
    uint32_t* binB     = (uint32_t*)(w + 0);        // 80*4096*2*4 = 2621440
    int*      sel      = (int*)(w + 2621440);       // 1280 -> 2622720
    uint32_t* outCount = (uint32_t*)(w + 2622720);  // 320  -> 2623040
    uint32_t* binBCnt  = (uint32_t*)(w + 2623040);  // 320  -> 2623360
    float*    T        = (float*)(w + 2623360);     // 1152 -> 2624512
    uint32_t* outCand  = (uint32_t*)(w + 2624512);  // 640000 -> 3264512
    uint64_t* keys     = (uint64_t*)(w + 3520000);  // 1048576 -> 4568576
    // prep outputs (alive k_prep -> k_nms; overlap dead histB/binB/sel/T/outCand):
    float4*   boff     = (float4*)(w + 0);          // 1280000
    float*    area     = (float*)(w + 1280000);     // 320000 -> 1600000
    float4*   bclipb   = (float4*)(w + 1600000);    // 1280000 -> 2880000
    float*    scs      = (float*)(w + 2880000);     // 320000 -> 3200000
    int*      clss     = (int*)(w + 3200000);       // 320000 -> 3520000

    hipMemsetAsync(w + 2622720, 0, 640, stream);    // outCount + binBCnt only

    k_thr<<<(NBINS + 63) / 64, 64, 0, stream>>>(T);
    k_hist<<<NCHUNK, 256, 0, stream>>>(P, T, histB);
    k_scan<<<80, 256, 0, stream>>>(histB, sel);
    k_pass2<<<NCHUNK, 256, 0, stream>>>(P, sel, T, outCand, outCount, binB, binBCnt);
    k_selsort<<<80, 256, 0, stream>>>(sel, binB, binBCnt, outCand);
    k_keys<<<(NIMG * SORTN + 255) / 256, 256, 0, stream>>>(P, outCand, sel, binBCnt, keys);
    k_sort<<<NIMG, 1024, 0, stream>>>(keys);
    k_prep<<<(NIMG * MTOT + 255) / 256, 256, 0, stream>>>(P, keys, boff, area, bclipb, scs, clss);
    k_nms<<<NIMG, 256, 0, stream>>>(boff, area, bclipb, scs, clss, (float*)d_out);
}

// Round 5
// 302.111 us; speedup vs baseline: 6.8622x; 1.7664x over previous
//
#include <hip/hip_runtime.h>
#include <stdint.h>
#include <math.h>

#define NLEV 5
#define NIMG 16
#define NCLS 80
#define TOPK 1000
#define MTOT 5000
#define LPAD 1024
#define BINBCAP 4096
#define NBINS 288
#define BIN0 7846
#define OUTK 100
#define CHUNK 16384
#define NCHUNK 1632
#define NMSW 512
#define NMSWORDS 16
#define MW 17
#define PCAP_MAIN 1024
#define PCAP_BND 2048

__device__ __constant__ int c_HW[NLEV]   = {15200, 3800, 950, 247, 70};
__device__ __constant__ int c_E[NLEV]    = {1216000, 304000, 76000, 19760, 5600};
__device__ __constant__ int c_cpr[NLEV]  = {75, 19, 5, 2, 1};            // chunks per (img,level) row
__device__ __constant__ int c_cbase[NLEV + 1] = {0, 1200, 1504, 1584, 1616, 1632};

struct Params {
    const float* cls[NLEV];
    const float* reg[NLEV];
    const float* anc[NLEV];
    const int* imsize;
};

// ---- shared decode (must be used identically by k_keys and k_prep) ----
__device__ inline void decode_entry(const Params& P, int img, int lvl, uint32_t idx,
                                    float bclip[4], int* cls_out, bool* nonempty) {
    int HW = c_HW[lvl];
    int loc = (int)idx / NCLS;
    int c = (int)idx - loc * NCLS;
    const float* a = P.anc[lvl] + 4 * loc;
    float a0 = a[0], a1 = a[1], a2 = a[2], a3 = a[3];
    const float* rg = P.reg[lvl] + (size_t)img * 4 * HW + loc;
    float d0 = rg[0], d1 = rg[HW], d2 = rg[2 * HW], d3 = rg[3 * HW];
    float w = a2 - a0 + 1.0f, h = a3 - a1 + 1.0f;
    float cx = a0 + 0.5f * w, cy = a1 + 0.5f * h;
    float dx = d0 / 10.0f, dy = d1 / 10.0f;
    const float SCALE_CLAMP = 4.135166556742356f;
    float dw = fminf(d2 / 5.0f, SCALE_CLAMP);
    float dh = fminf(d3 / 5.0f, SCALE_CLAMP);
    float pcx = dx * w + cx, pcy = dy * h + cy;
    float pw = (float)exp((double)dw) * w;
    float ph = (float)exp((double)dh) * h;
    float x1 = pcx - 0.5f * (pw - 1.0f), y1 = pcy - 0.5f * (ph - 1.0f);
    float x2 = pcx + 0.5f * (pw - 1.0f), y2 = pcy + 0.5f * (ph - 1.0f);
    float Hs = (float)P.imsize[img * 2 + 0];
    float Ws = (float)P.imsize[img * 2 + 1];
    float x1c = fminf(fmaxf(x1, 0.0f), Ws);
    float y1c = fminf(fmaxf(y1, 0.0f), Hs);
    float x2c = fminf(fmaxf(x2, 0.0f), Ws);
    float y2c = fminf(fmaxf(y2, 0.0f), Hs);
    bclip[0] = x1c; bclip[1] = y1c; bclip[2] = x2c; bclip[3] = y2c;
    *cls_out = c;
    *nonempty = ((x2c - x1c) > 0.0f) && ((y2c - y1c) > 0.0f);
}

__device__ inline float sigmoid_f(float x) {
    return (float)(1.0 / (1.0 + exp(-(double)x)));
}

// ordered-uint <-> float (monotone bijection) for threshold bisection
__device__ inline uint32_t f2o(float f) {
    uint32_t b = __float_as_uint(f);
    return (b & 0x80000000u) ? ~b : (b | 0x80000000u);
}
__device__ inline float o2f(uint32_t o) {
    uint32_t b = (o & 0x80000000u) ? (o & 0x7FFFFFFFu) : ~o;
    return __uint_as_float(b);
}

// chunk -> (level, img, element range) mapping shared by k_hist / k_pass2
__device__ inline void chunk_map(int bid, int* lvl, int* img, int* start, int* end) {
    int l = 0;
#pragma unroll
    for (int q = 1; q < NLEV; q++) if (bid >= c_cbase[q]) l = q;
    int r = bid - c_cbase[l];
    int cpr = c_cpr[l];
    int im = r / cpr;
    int ch = r - im * cpr;
    int E = c_E[l];
    int st = ch * CHUNK;
    *lvl = l; *img = im; *start = st; *end = min(st + CHUNK, E);
}

// ---- K0: per-bin minimal-logit thresholds T[b] (monotone bisection) ----
__global__ void k_thr(float* T) {
    int b = blockIdx.x * blockDim.x + threadIdx.x;
    if (b >= NBINS) return;
    uint32_t lo = f2o(-4.0f), hi = f2o(20.0f);
    while (hi - lo > 1u) {
        uint32_t mid = lo + ((hi - lo) >> 1);
        float xm = o2f(mid);
        float s = sigmoid_f(xm);
        bool pass = (s > 0.05f) && (((int)(__float_as_uint(s) >> 17) - BIN0) >= b);
        if (pass) hi = mid; else lo = mid;
    }
    float xr = o2f(hi);
    float sv = sigmoid_f(xr);
    bool ok = (sv > 0.05f) && (((int)(__float_as_uint(sv) >> 17) - BIN0) >= b);
    T[b] = ok ? xr : __uint_as_float(0x7F800000u);   // unreachable bins -> +INF
}

// ---- K1: per-chunk private histogram; estimate bin, exact fix-up vs T ----
__global__ __launch_bounds__(256) void k_hist(Params P, const float* T, uint32_t* histB) {
    __shared__ uint32_t lh[NBINS];
    __shared__ float sT[NBINS];
    int l, img, start, end;
    chunk_map(blockIdx.x, &l, &img, &start, &end);
    for (int b = threadIdx.x; b < NBINS; b += 256) { lh[b] = 0; sT[b] = T[b]; }
    __syncthreads();
    float t0 = sT[0];
    const float4* p = (const float4*)(P.cls[l] + (size_t)img * c_E[l] + start);
    int n4 = (end - start) >> 2;
    for (int v = threadIdx.x; v < n4; v += 256) {
        float4 x4 = p[v];
        float xs[4] = {x4.x, x4.y, x4.z, x4.w};
#pragma unroll
        for (int k = 0; k < 4; k++) {
            float xv = xs[k];
            if (xv >= t0) {                       // exact pass-threshold
                float se = 1.0f / (1.0f + __expf(-xv));   // estimator only
                int b = (int)(__float_as_uint(se) >> 17) - BIN0;
                b = min(max(b, 0), NBINS - 1);
                while (b > 0 && xv < sT[b]) b--;          // exact fix-up:
                while (b + 1 < NBINS && xv >= sT[b + 1]) b++;  // T[b]<=x<T[b+1]
                atomicAdd(&lh[b], 1u);
            }
        }
    }
    __syncthreads();
    uint32_t* hb = histB + (size_t)blockIdx.x * NBINS;
    for (int b = threadIdx.x; b < NBINS; b += 256) hb[b] = lh[b];
}

// ---- K2: reduce per-chunk histograms, scan top-down for boundary bin ----
__global__ __launch_bounds__(256) void k_scan(const uint32_t* histB, int* sel) {
    __shared__ uint32_t lh[NBINS];
    int row = blockIdx.x;
    int l = row / NIMG, img = row - l * NIMG;
    int cb = c_cbase[l] + img * c_cpr[l];
    int nc = c_cpr[l];
    for (int b = threadIdx.x; b < NBINS; b += 256) {
        uint32_t s = 0;
        for (int c = 0; c < nc; c++) s += histB[(size_t)(cb + c) * NBINS + b];
        lh[b] = s;
    }
    __syncthreads();
    if (threadIdx.x == 0) {
        int cum = 0, B = -1, need = 0, cab = 0;
        for (int b = NBINS - 1; b >= 0; b--) {
            int c = (int)lh[b];
            if (cum + c >= TOPK) { B = b; cab = cum; need = TOPK - cum; break; }
            cum += c;
        }
        if (B < 0) { cab = cum; need = 0; }
        sel[row * 4 + 0] = B;
        sel[row * 4 + 1] = cab;
        sel[row * 4 + 2] = need;
        sel[row * 4 + 3] = cum;
    }
}

// ---- K3: compact candidates; LDS-privatized, one range-reserve per block ----
__global__ __launch_bounds__(256) void k_pass2(Params P, const int* sel, const float* T,
                                               uint32_t* outCand, uint32_t* outCount,
                                               uint32_t* binB, uint32_t* binBCnt) {
    __shared__ uint64_t smain[PCAP_MAIN];
    __shared__ uint64_t sbnd[PCAP_BND];
    __shared__ uint32_t cnt2[2];
    __shared__ uint32_t base2[2];
    int l, img, start, end;
    chunk_map(blockIdx.x, &l, &img, &start, &end);
    int row = l * NIMG + img;
    int B = sel[row * 4 + 0];
    float xt = T[max(B, 0)];
    int HW = c_HW[l];
    if (threadIdx.x < 2) cnt2[threadIdx.x] = 0;
    __syncthreads();
    const float4* p = (const float4*)(P.cls[l] + (size_t)img * c_E[l] + start);
    int n4 = (end - start) >> 2;
    for (int v = threadIdx.x; v < n4; v += 256) {
        float4 x4 = p[v];
        float xs[4] = {x4.x, x4.y, x4.z, x4.w};
#pragma unroll
        for (int k = 0; k < 4; k++) {
            float xv = xs[k];
            if (xv >= xt) {                       // implies s>0.05f && bin>=B
                float s = sigmoid_f(xv);          // exact bits for the key
                uint32_t bits = __float_as_uint(s);
                int bin = (int)(bits >> 17) - BIN0;
                int q2 = start + v * 4 + k;       // c*HW + p layout
                int c = q2 / HW;
                int pidx = q2 - c * HW;
                uint32_t idx = (uint32_t)(pidx * NCLS + c);
                uint64_t rec = ((uint64_t)bits << 32) | idx;
                if (bin > B) {
                    uint32_t lp = atomicAdd(&cnt2[0], 1u);
                    if (lp < PCAP_MAIN) smain[lp] = rec;   // cab<=999 -> never overflows
                    else {
                        uint32_t pos = atomicAdd(&outCount[row], 1u);
                        if (pos < TOPK)
                            ((uint2*)outCand)[(size_t)row * TOPK + pos] = make_uint2(bits, idx);
                    }
                } else {
                    uint32_t lp = atomicAdd(&cnt2[1], 1u);
                    if (lp < PCAP_BND) sbnd[lp] = rec;
                    else {
                        uint32_t p2 = atomicAdd(&binBCnt[row], 1u);
                        if (p2 < BINBCAP)
                            ((uint2*)binB)[(size_t)row * BINBCAP + p2] = make_uint2(bits, idx);
                    }
                }
            }
        }
    }
    __syncthreads();
    if (threadIdx.x == 0) base2[0] = atomicAdd(&outCount[row], min(cnt2[0], (uint32_t)PCAP_MAIN));
    if (threadIdx.x == 1) base2[1] = atomicAdd(&binBCnt[row], min(cnt2[1], (uint32_t)PCAP_BND));
    __syncthreads();
    uint32_t n0 = min(cnt2[0], (uint32_t)PCAP_MAIN);
    for (uint32_t i = threadIdx.x; i < n0; i += 256) {
        uint32_t pos = base2[0] + i;
        if (pos < TOPK) {
            uint64_t r = smain[i];
            ((uint2*)outCand)[(size_t)row * TOPK + pos] = make_uint2((uint32_t)(r >> 32), (uint32_t)r);
        }
    }
    uint32_t n1 = min(cnt2[1], (uint32_t)PCAP_BND);
    for (uint32_t i = threadIdx.x; i < n1; i += 256) {
        uint32_t pos = base2[1] + i;
        if (pos < BINBCAP) {
            uint64_t r = sbnd[i];
            ((uint2*)binB)[(size_t)row * BINBCAP + pos] = make_uint2((uint32_t)(r >> 32), (uint32_t)r);
        }
    }
}

// ---- K4: exact sort of boundary bin (dynamic pow2 size), append winners ----
__global__ __launch_bounds__(256) void k_selsort(const int* sel, const uint32_t* binB,
                                                 const uint32_t* binBCnt, uint32_t* outCand) {
    __shared__ uint64_t sk[BINBCAP];
    int row = blockIdx.x;
    int need = sel[row * 4 + 2];
    int cab = sel[row * 4 + 1];
    if (need <= 0) return;
    int cnt = min((int)binBCnt[row], BINBCAP);
    int N = 64; while (N < cnt) N <<= 1;     // dynamic sort size
    for (int i = threadIdx.x; i < N; i += blockDim.x) {
        uint64_t key = ~0ULL;
        if (i < cnt) {
            uint32_t b = binB[((size_t)row * BINBCAP + i) * 2 + 0];
            uint32_t idx = binB[((size_t)row * BINBCAP + i) * 2 + 1];
            key = ((uint64_t)(uint32_t)(~b) << 32) | idx;   // value desc, idx asc
        }
        sk[i] = key;
    }
    __syncthreads();
    for (int k = 2; k <= N; k <<= 1) {
        for (int j = k >> 1; j > 0; j >>= 1) {
            for (int i = threadIdx.x; i < N; i += blockDim.x) {
                int ixj = i ^ j;
                if (ixj > i) {
                    uint64_t A = sk[i], Bv = sk[ixj];
                    bool up = ((i & k) == 0);
                    if (up ? (A > Bv) : (A < Bv)) { sk[i] = Bv; sk[ixj] = A; }
                }
            }
            __syncthreads();
        }
    }
    int take = min(need, cnt);
    for (int i = threadIdx.x; i < take; i += blockDim.x) {
        uint64_t k = sk[i];
        uint32_t idx = (uint32_t)(k & 0xFFFFFFFFu);
        uint32_t bits = ~((uint32_t)(k >> 32));
        int pos = cab + i;
        outCand[((size_t)row * TOPK + pos) * 2 + 0] = bits;
        outCand[((size_t)row * TOPK + pos) * 2 + 1] = idx;
    }
}

// ---- K5: build 64-bit sort keys, layout [img][lvl][1024] (pad = ~0) ----
__global__ __launch_bounds__(256) void k_keys(Params P, const uint32_t* outCand,
                                              const int* sel, const uint32_t* binBCnt,
                                              uint64_t* keys) {
    int t = blockIdx.x * blockDim.x + threadIdx.x;
    if (t >= NIMG * NLEV * LPAD) return;
    int img = t / (NLEV * LPAD);
    int rem = t - img * (NLEV * LPAD);
    int lvl = rem >> 10;
    int slot = rem & (LPAD - 1);
    if (slot >= TOPK) { keys[t] = ~0ULL; return; }
    int row = lvl * NIMG + img;
    int Bq = sel[row * 4 + 0], cab = sel[row * 4 + 1];
    int need = sel[row * 4 + 2], cum = sel[row * 4 + 3];
    int cnt = min((int)binBCnt[row], BINBCAP);
    int filled = (Bq < 0) ? cum : (cab + min(need, cnt));
    uint32_t bits = 0, idx = 0;
    if (slot < filled) {
        uint2 r = ((const uint2*)outCand)[(size_t)row * TOPK + slot];
        bits = r.x; idx = r.y;
    }
    uint32_t be = 0;
    if (bits != 0) {
        float bc[4]; int cc; bool ne;
        decode_entry(P, img, lvl, idx, bc, &cc, &ne);
        if (ne) be = bits;
    }
    keys[t] = ((uint64_t)(uint32_t)(~be) << 24) | ((uint64_t)lvl << 21) | (uint64_t)idx;
}

// ---- K6a: per-(img,level) 1024-element LDS bitonic sort ----
__global__ __launch_bounds__(256) void k_rsort(uint64_t* keys) {
    __shared__ uint64_t sk[LPAD];
    uint64_t* g = keys + (size_t)blockIdx.x * LPAD;
    for (int i = threadIdx.x; i < LPAD; i += 256) sk[i] = g[i];
    __syncthreads();
    for (int k = 2; k <= LPAD; k <<= 1) {
        for (int j = k >> 1; j > 0; j >>= 1) {
            for (int i = threadIdx.x; i < LPAD; i += 256) {
                int ixj = i ^ j;
                if (ixj > i) {
                    uint64_t A = sk[i], Bv = sk[ixj];
                    bool up = ((i & k) == 0);
                    if (up ? (A > Bv) : (A < Bv)) { sk[i] = Bv; sk[ixj] = A; }
                }
            }
            __syncthreads();
        }
    }
    for (int i = threadIdx.x; i < LPAD; i += 256) g[i] = sk[i];
}

// ---- K6b: rank-merge 5 sorted lists per image (exact: keys never tie
//            cross-list since key embeds lvl; within-list rank = position) ----
__global__ __launch_bounds__(1024) void k_merge(const uint64_t* keys, uint64_t* keys2) {
    __shared__ uint64_t sl[NLEV * LPAD];   // 40 KB
    int img = blockIdx.x;
    const uint64_t* g = keys + (size_t)img * NLEV * LPAD;
    for (int i = threadIdx.x; i < NLEV * LPAD; i += 1024) sl[i] = g[i];
    __syncthreads();
    for (int e = threadIdx.x; e < NLEV * LPAD; e += 1024) {
        int l = e >> 10, i = e & (LPAD - 1);
        if (i >= TOPK) continue;           // sentinels sort to tail, never placed
        uint64_t K = sl[e];
        int rank = i;
#pragma unroll
        for (int l2 = 0; l2 < NLEV; l2++) {
            if (l2 == l) continue;
            const uint64_t* s2 = &sl[l2 << 10];
            int lo = 0, hi = TOPK;
            while (lo < hi) {
                int mid = (lo + hi) >> 1;
                if (s2[mid] < K) lo = mid + 1; else hi = mid;
            }
            rank += lo;
        }
        keys2[(size_t)img * MTOT + rank] = K;
    }
}

// ---- K7: decode sorted entries into NMS-ready arrays ----
__global__ __launch_bounds__(256) void k_prep(Params P, const uint64_t* keys2, float4* boff,
                                              float* area, float4* bclip, float* scs, int* clss) {
    int t = blockIdx.x * blockDim.x + threadIdx.x;
    if (t >= NIMG * MTOT) return;
    int img = t / MTOT;
    int e = t - img * MTOT;
    uint64_t k = keys2[(size_t)img * MTOT + e];
    uint32_t bits = ~((uint32_t)(k >> 24));
    int lvl = (int)((k >> 21) & 7);
    uint32_t idx = (uint32_t)(k & 0x1FFFFF);
    float bc[4]; int cc; bool ne;
    decode_entry(P, img, lvl, idx, bc, &cc, &ne);
    float sc = 0.0f;
    if (bits != 0) {
        float s = __uint_as_float(bits);
        sc = sqrtf(fmaxf(s, 1e-12f));
    }
    float off = (float)cc * 2000.0f;
    float b0 = bc[0] + off, b1 = bc[1] + off, b2 = bc[2] + off, b3 = bc[3] + off;
    boff[t] = make_float4(b0, b1, b2, b3);
    area[t] = (b2 - b0) * (b3 - b1);
    bclip[t] = make_float4(bc[0], bc[1], bc[2], bc[3]);
    scs[t] = sc;
    clss[t] = cc;
}

// ---- K8: windowed exact greedy NMS (bit-matrix + wave-lockstep scan) ----
__global__ __launch_bounds__(256) void k_nms(const float4* boff, const float* area,
                                             const float4* bclip, const float* scs,
                                             const int* clss, float* out) {
    int img = blockIdx.x;
    const float4* bo = boff + (size_t)img * MTOT;
    const float* ar = area + (size_t)img * MTOT;
    const float4* bclp = bclip + (size_t)img * MTOT;
    const float* sc = scs + (size_t)img * MTOT;
    const int* cl = clss + (size_t)img * MTOT;

    __shared__ float sx1[NMSW], sy1[NMSW], sx2[NMSW], sy2[NMSW], sar[NMSW], ssc[NMSW];
    __shared__ uint32_t mask[NMSW * MW];
    __shared__ uint32_t presup[NMSWORDS];
    __shared__ uint32_t gsup[160];
    __shared__ float kx1[OUTK], ky1[OUTK], kx2[OUTK], ky2[OUTK], kar[OUTK];
    __shared__ int keptIdx[OUTK];
    __shared__ int s_kc, s_done;

    int tid = threadIdx.x;
    if (tid == 0) { s_kc = 0; s_done = 0; }
    __syncthreads();

    for (int wstart = 0; wstart < MTOT; wstart += NMSW) {
        int L = min(NMSW, MTOT - wstart);
        for (int j = tid; j < NMSW; j += 256) {
            if (j < L) {
                float4 b = bo[wstart + j];
                sx1[j] = b.x; sy1[j] = b.y; sx2[j] = b.z; sy2[j] = b.w;
                sar[j] = ar[wstart + j];
                ssc[j] = sc[wstart + j];
            } else {
                ssc[j] = 0.0f;
            }
        }
        __syncthreads();
        int kc0 = s_kc;
        if (tid < NMSWORDS) {
            uint32_t m = 0;
            for (int b = 0; b < 32; b++) {
                int j = tid * 32 + b;
                if (j >= L || ssc[j] == 0.0f) m |= 1u << b;
            }
            presup[tid] = m;
        }
        __syncthreads();
        if (kc0 > 0) {
            for (int j = tid; j < L; j += 256) {
                if (ssc[j] == 0.0f) continue;
                float bx1 = sx1[j], by1 = sy1[j], bx2 = sx2[j], by2 = sy2[j], baj = sar[j];
                bool supd = false;
                for (int k = 0; k < kc0; k++) {
                    float xx1 = fmaxf(kx1[k], bx1), yy1 = fmaxf(ky1[k], by1);
                    float xx2 = fminf(kx2[k], bx2), yy2 = fminf(ky2[k], by2);
                    float inter = fmaxf(xx2 - xx1, 0.0f) * fmaxf(yy2 - yy1, 0.0f);
                    float iou = inter / (kar[k] + baj - inter + 1e-9f);
                    if (iou > 0.6f) supd = true;
                }
                if (supd) atomicOr(&presup[j >> 5], 1u << (j & 31));
            }
            __syncthreads();
        }
        for (int i = tid; i < NMSW; i += 256) {
            if (i < L) {
                float bx1 = sx1[i], by1 = sy1[i], bx2 = sx2[i], by2 = sy2[i], bai = sar[i];
                for (int w = 0; w < NMSWORDS; w++) {
                    uint32_t m = 0;
                    int j0 = max(w * 32, i + 1);
                    int j1 = min(w * 32 + 32, L);
                    for (int j = j0; j < j1; j++) {
                        float xx1 = fmaxf(bx1, sx1[j]), yy1 = fmaxf(by1, sy1[j]);
                        float xx2 = fminf(bx2, sx2[j]), yy2 = fminf(by2, sy2[j]);
                        float inter = fmaxf(xx2 - xx1, 0.0f) * fmaxf(yy2 - yy1, 0.0f);
                        float iou = inter / (bai + sar[j] - inter + 1e-9f);
                        if (iou > 0.6f) m |= 1u << (j - w * 32);
                    }
                    mask[i * MW + w] = m;
                }
            }
        }
        __syncthreads();
        if (tid < 64) {
            int lane = tid;
            uint32_t supw = (lane < NMSWORDS) ? presup[lane] : 0xFFFFFFFFu;
            int kc = kc0;
            for (int i = 0; i < L; i++) {
                uint32_t wv = __shfl(supw, i >> 5);
                if (!((wv >> (i & 31)) & 1u)) {
                    if (lane == 0) {
                        keptIdx[kc] = wstart + i;
                        kx1[kc] = sx1[i]; ky1[kc] = sy1[i];
                        kx2[kc] = sx2[i]; ky2[kc] = sy2[i];
                        kar[kc] = sar[i];
                    }
                    if (lane < NMSWORDS) supw |= mask[i * MW + lane];
                    kc++;
                    if (kc == OUTK) { if (lane == 0) { s_kc = kc; s_done = 1; } break; }
                }
            }
            if (lane == 0 && s_done == 0) s_kc = kc;
            if (lane < NMSWORDS) gsup[(wstart >> 5) + lane] = supw;
        }
        __syncthreads();
        if (s_done) break;
    }

    int kc = s_kc;
    if (tid == 0 && kc < OUTK) {
        int k2 = kc;
        for (int e = 0; e < MTOT && k2 < OUTK; e++) {
            if ((gsup[e >> 5] >> (e & 31)) & 1u) keptIdx[k2++] = e | (1 << 30);
        }
    }
    __syncthreads();

    for (int t = tid; t < OUTK; t += 256) {
        int ke = keptIdx[t];
        bool fil = (ke >> 30) & 1;
        int e = ke & 0x3FFFFFFF;
        float4 b = bclp[e];
        out[((size_t)img * OUTK + t) * 4 + 0] = b.x;
        out[((size_t)img * OUTK + t) * 4 + 1] = b.y;
        out[((size_t)img * OUTK + t) * 4 + 2] = b.z;
        out[((size_t)img * OUTK + t) * 4 + 3] = b.w;
        out[NIMG * OUTK * 4 + img * OUTK + t] = fil ? 0.0f : sc[e];
        out[NIMG * OUTK * 4 + NIMG * OUTK + img * OUTK + t] = (float)cl[e];
    }
}

extern "C" void kernel_launch(void* const* d_in, const int* in_sizes, int n_in,
                              void* d_out, int out_size, void* d_ws, size_t ws_size,
                              hipStream_t stream) {
    Params P;
    for (int l = 0; l < 5; l++) {
        P.cls[l] = (const float*)d_in[l * 3 + 0];
        P.reg[l] = (const float*)d_in[l * 3 + 1];
        P.anc[l] = (const float*)d_in[l * 3 + 2];
    }
    P.imsize = (const int*)d_in[15];

    char* w = (char*)d_ws;
    // Lifetime-aliased layout (total 5,458,432 bytes):
    //  region A [0..3,520,000): histB (K1->K2) | binB (K3->K4) | prep outputs (K7->K8)
    uint32_t* histB    = (uint32_t*)(w + 0);        // 1632*288*4 = 1,880,064
    uint32_t* binB     = (uint32_t*)(w + 0);        // 80*4096*8  = 2,621,440
    float4*   boff     = (float4*)(w + 0);          // 1,280,000
    float*    area     = (float*)(w + 1280000);     // 320,000 -> 1,600,000
    float4*   bclipb   = (float4*)(w + 1600000);    // 1,280,000 -> 2,880,000
    float*    scs      = (float*)(w + 2880000);     // 320,000 -> 3,200,000
    int*      clss     = (int*)(w + 3200000);       // 320,000 -> 3,520,000
    int*      sel      = (int*)(w + 3520000);       // 1,280 -> 3,521,280
    uint32_t* outCount = (uint32_t*)(w + 3521280);  // 320 -> 3,521,600
    uint32_t* binBCnt  = (uint32_t*)(w + 3521600);  // 320 -> 3,521,920
    float*    T        = (float*)(w + 3521920);     // 1,152 -> 3,523,072
    uint32_t* outCand  = (uint32_t*)(w + 3523072);  // 640,000 -> 4,163,072
    uint64_t* keys     = (uint64_t*)(w + 4163072);  // 16*5120*8 = 655,360 -> 4,818,432
    uint64_t* keys2    = (uint64_t*)(w + 4818432);  // 16*5000*8 = 640,000 -> 5,458,432

    hipMemsetAsync(w + 3521280, 0, 640, stream);    // outCount + binBCnt only

    k_thr<<<(NBINS + 63) / 64, 64, 0, stream>>>(T);
    k_hist<<<NCHUNK, 256, 0, stream>>>(P, T, histB);
    k_scan<<<80, 256, 0, stream>>>(histB, sel);
    k_pass2<<<NCHUNK, 256, 0, stream>>>(P, sel, T, outCand, outCount, binB, binBCnt);
    k_selsort<<<80, 256, 0, stream>>>(sel, binB, binBCnt, outCand);
    k_keys<<<(NIMG * NLEV * LPAD + 255) / 256, 256, 0, stream>>>(P, outCand, sel, binBCnt, keys);
    k_rsort<<<NIMG * NLEV, 256, 0, stream>>>(keys);
    k_merge<<<NIMG, 1024, 0, stream>>>(keys, keys2);
    k_prep<<<(NIMG * MTOT + 255) / 256, 256, 0, stream>>>(P, keys2, boff, area, bclipb, scs, clss);
    k_nms<<<NIMG, 256, 0, stream>>>(boff, area, bclipb, scs, clss, (float*)d_out);
}

// Round 6
// 282.673 us; speedup vs baseline: 7.3341x; 1.0688x over previous
//
#include <hip/hip_runtime.h>
#include <stdint.h>
#include <math.h>

#define NLEV 5
#define NIMG 16
#define NCLS 80
#define TOPK 1000
#define MTOT 5000
#define LPAD 1024
#define BINBCAP 4096
#define NBINS 288
#define BIN0 7846
#define OUTK 100
#define CHUNK 16384
#define NCHUNK 1632
#define NMSW 512
#define PCAP_MAIN 1024
#define PCAP_BND 2048

__device__ __constant__ int c_HW[NLEV]   = {15200, 3800, 950, 247, 70};
__device__ __constant__ int c_E[NLEV]    = {1216000, 304000, 76000, 19760, 5600};
__device__ __constant__ int c_cpr[NLEV]  = {75, 19, 5, 2, 1};            // chunks per (img,level) row
__device__ __constant__ int c_cbase[NLEV + 1] = {0, 1200, 1504, 1584, 1616, 1632};

struct Params {
    const float* cls[NLEV];
    const float* reg[NLEV];
    const float* anc[NLEV];
    const int* imsize;
};

// ---- shared decode (must be used identically by k_keys and k_prep) ----
__device__ inline void decode_entry(const Params& P, int img, int lvl, uint32_t idx,
                                    float bclip[4], int* cls_out, bool* nonempty) {
    int HW = c_HW[lvl];
    int loc = (int)idx / NCLS;
    int c = (int)idx - loc * NCLS;
    const float* a = P.anc[lvl] + 4 * loc;
    float a0 = a[0], a1 = a[1], a2 = a[2], a3 = a[3];
    const float* rg = P.reg[lvl] + (size_t)img * 4 * HW + loc;
    float d0 = rg[0], d1 = rg[HW], d2 = rg[2 * HW], d3 = rg[3 * HW];
    float w = a2 - a0 + 1.0f, h = a3 - a1 + 1.0f;
    float cx = a0 + 0.5f * w, cy = a1 + 0.5f * h;
    float dx = d0 / 10.0f, dy = d1 / 10.0f;
    const float SCALE_CLAMP = 4.135166556742356f;
    float dw = fminf(d2 / 5.0f, SCALE_CLAMP);
    float dh = fminf(d3 / 5.0f, SCALE_CLAMP);
    float pcx = dx * w + cx, pcy = dy * h + cy;
    float pw = (float)exp((double)dw) * w;
    float ph = (float)exp((double)dh) * h;
    float x1 = pcx - 0.5f * (pw - 1.0f), y1 = pcy - 0.5f * (ph - 1.0f);
    float x2 = pcx + 0.5f * (pw - 1.0f), y2 = pcy + 0.5f * (ph - 1.0f);
    float Hs = (float)P.imsize[img * 2 + 0];
    float Ws = (float)P.imsize[img * 2 + 1];
    float x1c = fminf(fmaxf(x1, 0.0f), Ws);
    float y1c = fminf(fmaxf(y1, 0.0f), Hs);
    float x2c = fminf(fmaxf(x2, 0.0f), Ws);
    float y2c = fminf(fmaxf(y2, 0.0f), Hs);
    bclip[0] = x1c; bclip[1] = y1c; bclip[2] = x2c; bclip[3] = y2c;
    *cls_out = c;
    *nonempty = ((x2c - x1c) > 0.0f) && ((y2c - y1c) > 0.0f);
}

__device__ inline float sigmoid_f(float x) {
    return (float)(1.0 / (1.0 + exp(-(double)x)));
}

// ordered-uint <-> float (monotone bijection) for threshold bisection
__device__ inline uint32_t f2o(float f) {
    uint32_t b = __float_as_uint(f);
    return (b & 0x80000000u) ? ~b : (b | 0x80000000u);
}
__device__ inline float o2f(uint32_t o) {
    uint32_t b = (o & 0x80000000u) ? (o & 0x7FFFFFFFu) : ~o;
    return __uint_as_float(b);
}

// chunk -> (level, img, element range) mapping shared by k_hist / k_pass2
__device__ inline void chunk_map(int bid, int* lvl, int* img, int* start, int* end) {
    int l = 0;
#pragma unroll
    for (int q = 1; q < NLEV; q++) if (bid >= c_cbase[q]) l = q;
    int r = bid - c_cbase[l];
    int cpr = c_cpr[l];
    int im = r / cpr;
    int ch = r - im * cpr;
    int E = c_E[l];
    int st = ch * CHUNK;
    *lvl = l; *img = im; *start = st; *end = min(st + CHUNK, E);
}

// ---- K0: per-bin minimal-logit thresholds T[b] (monotone bisection) ----
__global__ void k_thr(float* T) {
    int b = blockIdx.x * blockDim.x + threadIdx.x;
    if (b >= NBINS) return;
    uint32_t lo = f2o(-4.0f), hi = f2o(20.0f);
    while (hi - lo > 1u) {
        uint32_t mid = lo + ((hi - lo) >> 1);
        float xm = o2f(mid);
        float s = sigmoid_f(xm);
        bool pass = (s > 0.05f) && (((int)(__float_as_uint(s) >> 17) - BIN0) >= b);
        if (pass) hi = mid; else lo = mid;
    }
    float xr = o2f(hi);
    float sv = sigmoid_f(xr);
    bool ok = (sv > 0.05f) && (((int)(__float_as_uint(sv) >> 17) - BIN0) >= b);
    T[b] = ok ? xr : __uint_as_float(0x7F800000u);   // unreachable bins -> +INF
}

// ---- K1: per-chunk private histogram; estimate bin, exact fix-up vs T ----
__global__ __launch_bounds__(256) void k_hist(Params P, const float* T, uint32_t* histB) {
    __shared__ uint32_t lh[NBINS];
    __shared__ float sT[NBINS];
    int l, img, start, end;
    chunk_map(blockIdx.x, &l, &img, &start, &end);
    for (int b = threadIdx.x; b < NBINS; b += 256) { lh[b] = 0; sT[b] = T[b]; }
    __syncthreads();
    float t0 = sT[0];
    const float4* p = (const float4*)(P.cls[l] + (size_t)img * c_E[l] + start);
    int n4 = (end - start) >> 2;
    for (int v = threadIdx.x; v < n4; v += 256) {
        float4 x4 = p[v];
        float xs[4] = {x4.x, x4.y, x4.z, x4.w};
#pragma unroll
        for (int k = 0; k < 4; k++) {
            float xv = xs[k];
            if (xv >= t0) {                       // exact pass-threshold
                float se = 1.0f / (1.0f + __expf(-xv));   // estimator only
                int b = (int)(__float_as_uint(se) >> 17) - BIN0;
                b = min(max(b, 0), NBINS - 1);
                while (b > 0 && xv < sT[b]) b--;          // exact fix-up:
                while (b + 1 < NBINS && xv >= sT[b + 1]) b++;  // T[b]<=x<T[b+1]
                atomicAdd(&lh[b], 1u);
            }
        }
    }
    __syncthreads();
    uint32_t* hb = histB + (size_t)blockIdx.x * NBINS;
    for (int b = threadIdx.x; b < NBINS; b += 256) hb[b] = lh[b];
}

// ---- K2: reduce per-chunk histograms, scan top-down for boundary bin ----
__global__ __launch_bounds__(256) void k_scan(const uint32_t* histB, int* sel) {
    __shared__ uint32_t lh[NBINS];
    int row = blockIdx.x;
    int l = row / NIMG, img = row - l * NIMG;
    int cb = c_cbase[l] + img * c_cpr[l];
    int nc = c_cpr[l];
    for (int b = threadIdx.x; b < NBINS; b += 256) {
        uint32_t s = 0;
        for (int c = 0; c < nc; c++) s += histB[(size_t)(cb + c) * NBINS + b];
        lh[b] = s;
    }
    __syncthreads();
    if (threadIdx.x == 0) {
        int cum = 0, B = -1, need = 0, cab = 0;
        for (int b = NBINS - 1; b >= 0; b--) {
            int c = (int)lh[b];
            if (cum + c >= TOPK) { B = b; cab = cum; need = TOPK - cum; break; }
            cum += c;
        }
        if (B < 0) { cab = cum; need = 0; }
        sel[row * 4 + 0] = B;
        sel[row * 4 + 1] = cab;
        sel[row * 4 + 2] = need;
        sel[row * 4 + 3] = cum;
    }
}

// ---- K3: compact candidates; LDS-privatized, one range-reserve per block ----
__global__ __launch_bounds__(256) void k_pass2(Params P, const int* sel, const float* T,
                                               uint32_t* outCand, uint32_t* outCount,
                                               uint32_t* binB, uint32_t* binBCnt) {
    __shared__ uint64_t smain[PCAP_MAIN];
    __shared__ uint64_t sbnd[PCAP_BND];
    __shared__ uint32_t cnt2[2];
    __shared__ uint32_t base2[2];
    int l, img, start, end;
    chunk_map(blockIdx.x, &l, &img, &start, &end);
    int row = l * NIMG + img;
    int B = sel[row * 4 + 0];
    float xt = T[max(B, 0)];
    int HW = c_HW[l];
    if (threadIdx.x < 2) cnt2[threadIdx.x] = 0;
    __syncthreads();
    const float4* p = (const float4*)(P.cls[l] + (size_t)img * c_E[l] + start);
    int n4 = (end - start) >> 2;
    for (int v = threadIdx.x; v < n4; v += 256) {
        float4 x4 = p[v];
        float xs[4] = {x4.x, x4.y, x4.z, x4.w};
#pragma unroll
        for (int k = 0; k < 4; k++) {
            float xv = xs[k];
            if (xv >= xt) {                       // implies s>0.05f && bin>=B
                float s = sigmoid_f(xv);          // exact bits for the key
                uint32_t bits = __float_as_uint(s);
                int bin = (int)(bits >> 17) - BIN0;
                int q2 = start + v * 4 + k;       // c*HW + p layout
                int c = q2 / HW;
                int pidx = q2 - c * HW;
                uint32_t idx = (uint32_t)(pidx * NCLS + c);
                uint64_t rec = ((uint64_t)bits << 32) | idx;
                if (bin > B) {
                    uint32_t lp = atomicAdd(&cnt2[0], 1u);
                    if (lp < PCAP_MAIN) smain[lp] = rec;   // cab<=999 -> never overflows
                    else {
                        uint32_t pos = atomicAdd(&outCount[row], 1u);
                        if (pos < TOPK)
                            ((uint2*)outCand)[(size_t)row * TOPK + pos] = make_uint2(bits, idx);
                    }
                } else {
                    uint32_t lp = atomicAdd(&cnt2[1], 1u);
                    if (lp < PCAP_BND) sbnd[lp] = rec;
                    else {
                        uint32_t p2 = atomicAdd(&binBCnt[row], 1u);
                        if (p2 < BINBCAP)
                            ((uint2*)binB)[(size_t)row * BINBCAP + p2] = make_uint2(bits, idx);
                    }
                }
            }
        }
    }
    __syncthreads();
    if (threadIdx.x == 0) base2[0] = atomicAdd(&outCount[row], min(cnt2[0], (uint32_t)PCAP_MAIN));
    if (threadIdx.x == 1) base2[1] = atomicAdd(&binBCnt[row], min(cnt2[1], (uint32_t)PCAP_BND));
    __syncthreads();
    uint32_t n0 = min(cnt2[0], (uint32_t)PCAP_MAIN);
    for (uint32_t i = threadIdx.x; i < n0; i += 256) {
        uint32_t pos = base2[0] + i;
        if (pos < TOPK) {
            uint64_t r = smain[i];
            ((uint2*)outCand)[(size_t)row * TOPK + pos] = make_uint2((uint32_t)(r >> 32), (uint32_t)r);
        }
    }
    uint32_t n1 = min(cnt2[1], (uint32_t)PCAP_BND);
    for (uint32_t i = threadIdx.x; i < n1; i += 256) {
        uint32_t pos = base2[1] + i;
        if (pos < BINBCAP) {
            uint64_t r = sbnd[i];
            ((uint2*)binB)[(size_t)row * BINBCAP + pos] = make_uint2((uint32_t)(r >> 32), (uint32_t)r);
        }
    }
}

// ---- K4: exact sort of boundary bin (dynamic pow2 size), append winners ----
__global__ __launch_bounds__(256) void k_selsort(const int* sel, const uint32_t* binB,
                                                 const uint32_t* binBCnt, uint32_t* outCand) {
    __shared__ uint64_t sk[BINBCAP];
    int row = blockIdx.x;
    int need = sel[row * 4 + 2];
    int cab = sel[row * 4 + 1];
    if (need <= 0) return;
    int cnt = min((int)binBCnt[row], BINBCAP);
    int N = 64; while (N < cnt) N <<= 1;     // dynamic sort size
    for (int i = threadIdx.x; i < N; i += blockDim.x) {
        uint64_t key = ~0ULL;
        if (i < cnt) {
            uint32_t b = binB[((size_t)row * BINBCAP + i) * 2 + 0];
            uint32_t idx = binB[((size_t)row * BINBCAP + i) * 2 + 1];
            key = ((uint64_t)(uint32_t)(~b) << 32) | idx;   // value desc, idx asc
        }
        sk[i] = key;
    }
    __syncthreads();
    for (int k = 2; k <= N; k <<= 1) {
        for (int j = k >> 1; j > 0; j >>= 1) {
            for (int i = threadIdx.x; i < N; i += blockDim.x) {
                int ixj = i ^ j;
                if (ixj > i) {
                    uint64_t A = sk[i], Bv = sk[ixj];
                    bool up = ((i & k) == 0);
                    if (up ? (A > Bv) : (A < Bv)) { sk[i] = Bv; sk[ixj] = A; }
                }
            }
            __syncthreads();
        }
    }
    int take = min(need, cnt);
    for (int i = threadIdx.x; i < take; i += blockDim.x) {
        uint64_t k = sk[i];
        uint32_t idx = (uint32_t)(k & 0xFFFFFFFFu);
        uint32_t bits = ~((uint32_t)(k >> 32));
        int pos = cab + i;
        outCand[((size_t)row * TOPK + pos) * 2 + 0] = bits;
        outCand[((size_t)row * TOPK + pos) * 2 + 1] = idx;
    }
}

// ---- K5: build 64-bit sort keys, layout [img][lvl][1024] (pad = ~0) ----
__global__ __launch_bounds__(256) void k_keys(Params P, const uint32_t* outCand,
                                              const int* sel, const uint32_t* binBCnt,
                                              uint64_t* keys) {
    int t = blockIdx.x * blockDim.x + threadIdx.x;
    if (t >= NIMG * NLEV * LPAD) return;
    int img = t / (NLEV * LPAD);
    int rem = t - img * (NLEV * LPAD);
    int lvl = rem >> 10;
    int slot = rem & (LPAD - 1);
    if (slot >= TOPK) { keys[t] = ~0ULL; return; }
    int row = lvl * NIMG + img;
    int Bq = sel[row * 4 + 0], cab = sel[row * 4 + 1];
    int need = sel[row * 4 + 2], cum = sel[row * 4 + 3];
    int cnt = min((int)binBCnt[row], BINBCAP);
    int filled = (Bq < 0) ? cum : (cab + min(need, cnt));
    uint32_t bits = 0, idx = 0;
    if (slot < filled) {
        uint2 r = ((const uint2*)outCand)[(size_t)row * TOPK + slot];
        bits = r.x; idx = r.y;
    }
    uint32_t be = 0;
    if (bits != 0) {
        float bc[4]; int cc; bool ne;
        decode_entry(P, img, lvl, idx, bc, &cc, &ne);
        if (ne) be = bits;
    }
    keys[t] = ((uint64_t)(uint32_t)(~be) << 24) | ((uint64_t)lvl << 21) | (uint64_t)idx;
}

// ---- K6a: per-(img,level) 1024-element LDS bitonic sort ----
__global__ __launch_bounds__(256) void k_rsort(uint64_t* keys) {
    __shared__ uint64_t sk[LPAD];
    uint64_t* g = keys + (size_t)blockIdx.x * LPAD;
    for (int i = threadIdx.x; i < LPAD; i += 256) sk[i] = g[i];
    __syncthreads();
    for (int k = 2; k <= LPAD; k <<= 1) {
        for (int j = k >> 1; j > 0; j >>= 1) {
            for (int i = threadIdx.x; i < LPAD; i += 256) {
                int ixj = i ^ j;
                if (ixj > i) {
                    uint64_t A = sk[i], Bv = sk[ixj];
                    bool up = ((i & k) == 0);
                    if (up ? (A > Bv) : (A < Bv)) { sk[i] = Bv; sk[ixj] = A; }
                }
            }
            __syncthreads();
        }
    }
    for (int i = threadIdx.x; i < LPAD; i += 256) g[i] = sk[i];
}

// ---- K6b: rank-merge 5 sorted lists per image (exact: keys never tie
//            cross-list since key embeds lvl; within-list rank = position) ----
__global__ __launch_bounds__(1024) void k_merge(const uint64_t* keys, uint64_t* keys2) {
    __shared__ uint64_t sl[NLEV * LPAD];   // 40 KB
    int img = blockIdx.x;
    const uint64_t* g = keys + (size_t)img * NLEV * LPAD;
    for (int i = threadIdx.x; i < NLEV * LPAD; i += 1024) sl[i] = g[i];
    __syncthreads();
    for (int e = threadIdx.x; e < NLEV * LPAD; e += 1024) {
        int l = e >> 10, i = e & (LPAD - 1);
        if (i >= TOPK) continue;           // sentinels sort to tail, never placed
        uint64_t K = sl[e];
        int rank = i;
#pragma unroll
        for (int l2 = 0; l2 < NLEV; l2++) {
            if (l2 == l) continue;
            const uint64_t* s2 = &sl[l2 << 10];
            int lo = 0, hi = TOPK;
            while (lo < hi) {
                int mid = (lo + hi) >> 1;
                if (s2[mid] < K) lo = mid + 1; else hi = mid;
            }
            rank += lo;
        }
        keys2[(size_t)img * MTOT + rank] = K;
    }
}

// ---- K7: decode sorted entries into NMS-ready arrays ----
__global__ __launch_bounds__(256) void k_prep(Params P, const uint64_t* keys2, float4* boff,
                                              float* area, float4* bclip, float* scs, int* clss) {
    int t = blockIdx.x * blockDim.x + threadIdx.x;
    if (t >= NIMG * MTOT) return;
    int img = t / MTOT;
    int e = t - img * MTOT;
    uint64_t k = keys2[(size_t)img * MTOT + e];
    uint32_t bits = ~((uint32_t)(k >> 24));
    int lvl = (int)((k >> 21) & 7);
    uint32_t idx = (uint32_t)(k & 0x1FFFFF);
    float bc[4]; int cc; bool ne;
    decode_entry(P, img, lvl, idx, bc, &cc, &ne);
    float sc = 0.0f;
    if (bits != 0) {
        float s = __uint_as_float(bits);
        sc = sqrtf(fmaxf(s, 1e-12f));
    }
    float off = (float)cc * 2000.0f;
    float b0 = bc[0] + off, b1 = bc[1] + off, b2 = bc[2] + off, b3 = bc[3] + off;
    boff[t] = make_float4(b0, b1, b2, b3);
    area[t] = (b2 - b0) * (b3 - b1);
    bclip[t] = make_float4(bc[0], bc[1], bc[2], bc[3]);
    scs[t] = sc;
    clss[t] = cc;
}

// ---- K8: register-resident windowed greedy NMS, one wave per image ----
// Window (512 boxes) lives in registers (8 chunks x 64 lanes). Suppression
// state = 8 x uint64, replicated in every lane via __ballot. IoU rows are
// computed ONLY for kept boxes (lazy), so cost ~ kept_count, not window^2.
__global__ __launch_bounds__(64) void k_nms(const float4* boff, const float* area,
                                            const float4* bclip, const float* scs,
                                            const int* clss, float* out) {
    int img = blockIdx.x;
    const float4* bo = boff + (size_t)img * MTOT;
    const float* ar = area + (size_t)img * MTOT;
    const float4* bclp = bclip + (size_t)img * MTOT;
    const float* sc = scs + (size_t)img * MTOT;
    const int* cl = clss + (size_t)img * MTOT;

    __shared__ float kx1[OUTK], ky1[OUTK], kx2[OUTK], ky2[OUTK], kar[OUTK];
    __shared__ int keptIdx[OUTK];
    __shared__ uint32_t gsup[160];

    int lane = threadIdx.x;
    int kc = 0;            // uniform across lanes
    bool done = false;     // uniform

    for (int wstart = 0; wstart < MTOT && !done; wstart += NMSW) {
        int L = min(NMSW, MTOT - wstart);
        // ---- load window into registers: 8 chunks of 64 ----
        float4 rb[8]; float ra[8]; float rs[8];
#pragma unroll
        for (int c = 0; c < 8; c++) {
            int j = wstart + c * 64 + lane;
            if (j < MTOT) { rb[c] = bo[j]; ra[c] = ar[j]; rs[c] = sc[j]; }
            else { rb[c] = make_float4(0.f, 0.f, 0.f, 0.f); ra[c] = 0.f; rs[c] = 0.f; }
        }
        __syncthreads();   // kept-list writes from previous window visible
        // ---- init masks: invalid or suppressed-by-kept (prior windows) ----
        uint64_t m[8];
#pragma unroll
        for (int c = 0; c < 8; c++) {
            int jl = c * 64 + lane;
            bool bad = (jl >= L) || (rs[c] == 0.0f);
            if (!bad && kc > 0) {
                float bx1 = rb[c].x, by1 = rb[c].y, bx2 = rb[c].z, by2 = rb[c].w;
                float baj = ra[c];
                for (int k = 0; k < kc; k++) {
                    float xx1 = fmaxf(kx1[k], bx1), yy1 = fmaxf(ky1[k], by1);
                    float xx2 = fminf(kx2[k], bx2), yy2 = fminf(ky2[k], by2);
                    float inter = fmaxf(xx2 - xx1, 0.0f) * fmaxf(yy2 - yy1, 0.0f);
                    float iou = inter / (kar[k] + baj - inter + 1e-9f);
                    if (iou > 0.6f) { bad = true; break; }
                }
            }
            m[c] = __ballot(bad);
        }
        // ---- greedy scan; lazy suppression rows for kept boxes only ----
#pragma unroll
        for (int c = 0; c < 8; c++) {
            for (int ii = 0; ii < 64; ii++) {
                int i = c * 64 + ii;
                if (done || i >= L) continue;              // uniform
                if ((m[c] >> ii) & 1ULL) continue;         // uniform (m replicated)
                float bx1 = __shfl(rb[c].x, ii);
                float by1 = __shfl(rb[c].y, ii);
                float bx2 = __shfl(rb[c].z, ii);
                float by2 = __shfl(rb[c].w, ii);
                float bai = __shfl(ra[c], ii);
                if (lane == 0) {
                    keptIdx[kc] = wstart + i;
                    kx1[kc] = bx1; ky1[kc] = by1; kx2[kc] = bx2; ky2[kc] = by2;
                    kar[kc] = bai;
                }
#pragma unroll
                for (int c2 = 0; c2 < 8; c2++) {
                    int j = c2 * 64 + lane;
                    float xx1 = fmaxf(bx1, rb[c2].x), yy1 = fmaxf(by1, rb[c2].y);
                    float xx2 = fminf(bx2, rb[c2].z), yy2 = fminf(by2, rb[c2].w);
                    float inter = fmaxf(xx2 - xx1, 0.0f) * fmaxf(yy2 - yy1, 0.0f);
                    float iou = inter / (bai + ra[c2] - inter + 1e-9f);
                    bool pr = (j > i) && (j < L) && (iou > 0.6f);
                    m[c2] |= __ballot(pr);
                }
                kc++;
                if (kc == OUTK) done = true;
            }
        }
        // ---- persist suppression bits for filler (only needed if !done) ----
        if (!done && lane == 0) {
#pragma unroll
            for (int c = 0; c < 8; c++) {
                gsup[(wstart >> 5) + 2 * c + 0] = (uint32_t)(m[c]);
                gsup[(wstart >> 5) + 2 * c + 1] = (uint32_t)(m[c] >> 32);
            }
        }
    }

    __syncthreads();
    // ---- filler: first suppressed/invalid entries in index order ----
    if (kc < OUTK) {
        if (lane == 0) {
            int k2 = kc;
            for (int e = 0; e < MTOT && k2 < OUTK; e++) {
                if ((gsup[e >> 5] >> (e & 31)) & 1u) keptIdx[k2++] = e | (1 << 30);
            }
        }
        __syncthreads();
    }

    for (int t = lane; t < OUTK; t += 64) {
        int ke = keptIdx[t];
        bool fil = (ke >> 30) & 1;
        int e = ke & 0x3FFFFFFF;
        float4 b = bclp[e];
        out[((size_t)img * OUTK + t) * 4 + 0] = b.x;
        out[((size_t)img * OUTK + t) * 4 + 1] = b.y;
        out[((size_t)img * OUTK + t) * 4 + 2] = b.z;
        out[((size_t)img * OUTK + t) * 4 + 3] = b.w;
        out[NIMG * OUTK * 4 + img * OUTK + t] = fil ? 0.0f : sc[e];
        out[NIMG * OUTK * 4 + NIMG * OUTK + img * OUTK + t] = (float)cl[e];
    }
}

extern "C" void kernel_launch(void* const* d_in, const int* in_sizes, int n_in,
                              void* d_out, int out_size, void* d_ws, size_t ws_size,
                              hipStream_t stream) {
    Params P;
    for (int l = 0; l < 5; l++) {
        P.cls[l] = (const float*)d_in[l * 3 + 0];
        P.reg[l] = (const float*)d_in[l * 3 + 1];
        P.anc[l] = (const float*)d_in[l * 3 + 2];
    }
    P.imsize = (const int*)d_in[15];

    char* w = (char*)d_ws;
    // Lifetime-aliased layout (total 5,458,432 bytes):
    //  region A [0..3,520,000): histB (K1->K2) | binB (K3->K4) | prep outputs (K7->K8)
    uint32_t* histB    = (uint32_t*)(w + 0);        // 1632*288*4 = 1,880,064
    uint32_t* binB     = (uint32_t*)(w + 0);        // 80*4096*8  = 2,621,440
    float4*   boff     = (float4*)(w + 0);          // 1,280,000
    float*    area     = (float*)(w + 1280000);     // 320,000 -> 1,600,000
    float4*   bclipb   = (float4*)(w + 1600000);    // 1,280,000 -> 2,880,000
    float*    scs      = (float*)(w + 2880000);     // 320,000 -> 3,200,000
    int*      clss     = (int*)(w + 3200000);       // 320,000 -> 3,520,000
    int*      sel      = (int*)(w + 3520000);       // 1,280 -> 3,521,280
    uint32_t* outCount = (uint32_t*)(w + 3521280);  // 320 -> 3,521,600
    uint32_t* binBCnt  = (uint32_t*)(w + 3521600);  // 320 -> 3,521,920
    float*    T        = (float*)(w + 3521920);     // 1,152 -> 3,523,072
    uint32_t* outCand  = (uint32_t*)(w + 3523072);  // 640,000 -> 4,163,072
    uint64_t* keys     = (uint64_t*)(w + 4163072);  // 16*5120*8 = 655,360 -> 4,818,432
    uint64_t* keys2    = (uint64_t*)(w + 4818432);  // 16*5000*8 = 640,000 -> 5,458,432

    hipMemsetAsync(w + 3521280, 0, 640, stream);    // outCount + binBCnt only

    k_thr<<<(NBINS + 63) / 64, 64, 0, stream>>>(T);
    k_hist<<<NCHUNK, 256, 0, stream>>>(P, T, histB);
    k_scan<<<80, 256, 0, stream>>>(histB, sel);
    k_pass2<<<NCHUNK, 256, 0, stream>>>(P, sel, T, outCand, outCount, binB, binBCnt);
    k_selsort<<<80, 256, 0, stream>>>(sel, binB, binBCnt, outCand);
    k_keys<<<(NIMG * NLEV * LPAD + 255) / 256, 256, 0, stream>>>(P, outCand, sel, binBCnt, keys);
    k_rsort<<<NIMG * NLEV, 256, 0, stream>>>(keys);
    k_merge<<<NIMG, 1024, 0, stream>>>(keys, keys2);
    k_prep<<<(NIMG * MTOT + 255) / 256, 256, 0, stream>>>(P, keys2, boff, area, bclipb, scs, clss);
    k_nms<<<NIMG, 64, 0, stream>>>(boff, area, bclipb, scs, clss, (float*)d_out);
}